// Round 1
// baseline (8184.480 us; speedup 1.0000x reference)
//
#include <hip/hip_runtime.h>
#include <cmath>
#include <cstring>
#include <complex>

#define NN 10000
#define NE 160000
#define HD 240
#define ZD 912
#define NG 64
#define MSG_WS 10496
#define UPD_WS 561152
#define LIN_WS 5376

// ---------------- kernarg coefficient structs ----------------
struct CMsgPre { float a000, a011, a110, a112, a211; float c101[9]; float c202[25]; };
struct CEdge   { float c011[9]; float c110[9]; float c112[45]; float c211[45]; };
struct CUpdS   { float s000; float c011[9]; float c022[25]; float c101[9]; float c202[25]; };
struct CUpdD   { float c110[9]; float c220[25]; };
struct CUpdP   { float c112[45]; float c121[45]; float c211[45]; float c222[125]; };

// ---------------- kernels ----------------

// per-edge: dist, unit vec, and the 36 w3j·n contraction values
__global__ __launch_bounds__(256) void k_edge_attr(
    const float* __restrict__ pos, const int* __restrict__ ei, CEdge C,
    float* __restrict__ EA, float* __restrict__ CN) {
  int e = blockIdx.x * 256 + threadIdx.x;
  if (e >= NE) return;
  int r = ei[e], c = ei[NE + e];
  float dx = pos[r*3+0] - pos[c*3+0];
  float dy = pos[r*3+1] - pos[c*3+1];
  float dz = pos[r*3+2] - pos[c*3+2];
  float d = sqrtf(dx*dx + dy*dy + dz*dz);
  float inv = 1.0f / fmaxf(d, 1e-8f);
  float n0 = dx*inv, n1 = dy*inv, n2 = dz*inv;
  EA[e*4+0] = d; EA[e*4+1] = n0; EA[e*4+2] = n1; EA[e*4+3] = n2;
  float* cn = CN + (size_t)e*36;
#pragma unroll
  for (int k = 0; k < 3; k++)
    cn[k] = n0*C.c011[0*3+k] + n1*C.c011[1*3+k] + n2*C.c011[2*3+k];
#pragma unroll
  for (int i = 0; i < 3; i++)
    cn[3+i] = n0*C.c110[i*3+0] + n1*C.c110[i*3+1] + n2*C.c110[i*3+2];
#pragma unroll
  for (int i = 0; i < 3; i++)
#pragma unroll
    for (int k = 0; k < 5; k++)
      cn[6+i*5+k] = n0*C.c112[(i*3+0)*5+k] + n1*C.c112[(i*3+1)*5+k] + n2*C.c112[(i*3+2)*5+k];
#pragma unroll
  for (int i = 0; i < 5; i++)
#pragma unroll
    for (int k = 0; k < 3; k++)
      cn[21+i*3+k] = n0*C.c211[(i*3+0)*3+k] + n1*C.c211[(i*3+1)*3+k] + n2*C.c211[(i*3+2)*3+k];
}

// h init: elem-major H[e][n]
__global__ __launch_bounds__(256) void k_h_init(
    const float* __restrict__ x, const float* __restrict__ wi, float* __restrict__ HT) {
  int n = blockIdx.x * 256 + threadIdx.x;
  int e = blockIdx.y;
  if (n >= NN) return;
  float v = 0.f;
  if (e < 64)
    v = (x[n*3+0]*wi[0*64+e] + x[n*3+1]*wi[64+e] + x[n*3+2]*wi[128+e]) * 0.57735026918962576f;
  HT[e*NN + n] = v;
}

// per-node msg precompute: z fragments (672) + msg-linear (240) -> Z[n][912] (node-major)
__global__ __launch_bounds__(256) void k_node_pre(
    const float* __restrict__ HT, const float* __restrict__ Wm, const float* __restrict__ Wl,
    CMsgPre C, float* __restrict__ Z) {
  int n = blockIdx.x * 256 + threadIdx.x;
  int widx = blockIdx.y;
  if (n >= NN) return;
  float acc = 0.f;
  if (widx < 64) {
    int w = widx;
    for (int u = 0; u < 64; u++) acc += HT[u*NN+n] * Wm[u*64+w];
    acc *= C.a000;
  } else if (widx < 96) {
    int w = widx - 64;
    for (int u = 0; u < 64; u++) acc += HT[u*NN+n] * Wm[4096 + u*32+w];
    acc *= C.a011;
  } else if (widx < 192) {
    int t = widx - 96, w = t/3, k = t - w*3;
    for (int u = 0; u < 32; u++) {
      float g = HT[(64+u*3+0)*NN+n]*C.c101[0*3+k]
              + HT[(64+u*3+1)*NN+n]*C.c101[1*3+k]
              + HT[(64+u*3+2)*NN+n]*C.c101[2*3+k];
      acc += Wm[6144 + u*32+w] * g;
    }
  } else if (widx < 384) {
    int t = widx - 192, w = t/3, i = t - w*3;
    for (int u = 0; u < 32; u++) acc += HT[(64+u*3+i)*NN+n] * Wm[7168 + u*64+w];
    acc *= C.a110;
  } else if (widx < 432) {
    int t = widx - 384, w = t/3, i = t - w*3;
    for (int u = 0; u < 32; u++) acc += HT[(64+u*3+i)*NN+n] * Wm[9216 + u*16+w];
    acc *= C.a112;
  } else if (widx < 512) {
    int t = widx - 432, w = t/5, k = t - w*5;
    for (int u = 0; u < 16; u++) {
      float g = 0.f;
#pragma unroll
      for (int i = 0; i < 5; i++) g += HT[(160+u*5+i)*NN+n] * C.c202[i*5+k];
      acc += Wm[9728 + u*16+w] * g;
    }
  } else if (widx < 672) {
    int t = widx - 512, w = t/5, i = t - w*5;
    for (int u = 0; u < 16; u++) acc += HT[(160+u*5+i)*NN+n] * Wm[9984 + u*32+w];
    acc *= C.a211;
  } else {
    int e2 = widx - 672;
    if (e2 < 64) {
      for (int u = 0; u < 64; u++) acc += HT[u*NN+n] * Wl[u*64+e2];
      acc *= 0.125f;
    } else if (e2 < 160) {
      int t = e2 - 64, v = t/3, i = t - v*3;
      for (int u = 0; u < 32; u++) acc += HT[(64+u*3+i)*NN+n] * Wl[4096 + u*32+v];
      acc *= 0.17677669529663687f;
    } else {
      int t = e2 - 160, v = t/5, i = t - v*5;
      for (int u = 0; u < 16; u++) acc += HT[(160+u*5+i)*NN+n] * Wl[5120 + u*16+v];
      acc *= 0.25f;
    }
  }
  Z[(size_t)n*ZD + widx] = acc;
}

// per-edge combine + scatter. one wave per edge, LDS-staged z record of col.
__global__ __launch_bounds__(256) void k_edge(
    const int* __restrict__ ei, const float* __restrict__ EA, const float* __restrict__ CN,
    const float* __restrict__ Z, float* __restrict__ AGG) {
  __shared__ float zsh[4][ZD];
  int lane = threadIdx.x & 63, wid = threadIdx.x >> 6;
  int wg = blockIdx.x * 4 + wid;
  int stride = gridDim.x * 4;
  int iters = (NE + stride - 1) / stride;
  for (int it = 0; it < iters; ++it) {
    int e = wg + it * stride;
    bool act = e < NE;
    int r = 0;
    float s = 0.f;
    const float* cn = CN;
    if (act) {
      r = ei[e];
      int c = ei[NE + e];
      s = EA[e*4];
      cn = CN + (size_t)e*36;
      const float* zr = Z + (size_t)c*ZD;
      for (int t = lane; t < ZD; t += 64) zsh[wid][t] = zr[t];
    }
    __syncthreads();
    if (act) {
      const float* z = zsh[wid];
#pragma unroll
      for (int j = 0; j < 4; j++) {
        int idx = lane + 64*j;
        if (idx < HD) {
          float y = z[672 + idx];  // msg-linear part
          if (idx < 64) {
            int w = idx;
            y += s * z[w];
#pragma unroll
            for (int i = 0; i < 3; i++) y += z[192 + w*3 + i] * cn[3+i];
          } else if (idx < 160) {
            int t = idx - 64, w = t/3, k = t - w*3;
            y += cn[k] * z[64 + w] + s * z[96 + t];
#pragma unroll
            for (int i = 0; i < 5; i++) y += z[512 + w*5 + i] * cn[21 + i*3 + k];
          } else {
            int t = idx - 160, w = t/5, k = t - w*5;
            y += s * z[432 + t];
#pragma unroll
            for (int i = 0; i < 3; i++) y += z[384 + w*3 + i] * cn[6 + i*5 + k];
          }
          atomicAdd(&AGG[(size_t)r*HD + idx], y);
        }
      }
    }
    __syncthreads();
  }
}

// transpose AGG node-major -> elem-major
__global__ __launch_bounds__(256) void k_transpose(
    const float* __restrict__ A_nm, float* __restrict__ A_t) {
  int n = blockIdx.x * 256 + threadIdx.x;
  int e = blockIdx.y;
  if (n >= NN) return;
  A_t[e*NN + n] = A_nm[(size_t)n*HD + e];
}

// update TP, "scalar-side" paths: (000),(011),(022),(101),(202)
__global__ __launch_bounds__(64) void k_upd_s(
    const float* __restrict__ HT, const float* __restrict__ AGT,
    const float* __restrict__ W, CUpdS C, float* __restrict__ UPD) {
  int n = blockIdx.x * 64 + threadIdx.x;
  if (n >= NN) return;
  int sy = blockIdx.y;
  if (sy < 4) {                       // (0,0,0)
    int w0 = sy * 16;
    float y[16];
#pragma unroll
    for (int w = 0; w < 16; w++) y[w] = 0.f;
    for (int u = 0; u < 64; u++) {
      float au = HT[u*NN+n] * C.s000;
      const float* Wu = W + u*64*64 + w0;
      for (int v = 0; v < 64; v++) {
        float p = au * AGT[v*NN+n];
        const float* Wp = Wu + v*64;
#pragma unroll
        for (int w = 0; w < 16; w++) y[w] += p * Wp[w];
      }
    }
#pragma unroll
    for (int w = 0; w < 16; w++) atomicAdd(&UPD[(w0+w)*NN + n], y[w]);
  } else if (sy < 8) {                // (0,1,1)
    int w0 = (sy-4) * 8;
    float y[24];
#pragma unroll
    for (int q = 0; q < 24; q++) y[q] = 0.f;
    for (int v = 0; v < 32; v++) {
      float b0 = AGT[(64+v*3+0)*NN+n], b1 = AGT[(64+v*3+1)*NN+n], b2 = AGT[(64+v*3+2)*NN+n];
      float bc[3];
#pragma unroll
      for (int k = 0; k < 3; k++) bc[k] = b0*C.c011[k] + b1*C.c011[3+k] + b2*C.c011[6+k];
      float g[8];
#pragma unroll
      for (int w = 0; w < 8; w++) g[w] = 0.f;
      for (int u = 0; u < 64; u++) {
        float au = HT[u*NN+n];
        const float* Wp = W + 262144 + (u*32+v)*32 + w0;
#pragma unroll
        for (int w = 0; w < 8; w++) g[w] += au * Wp[w];
      }
#pragma unroll
      for (int w = 0; w < 8; w++)
#pragma unroll
        for (int k = 0; k < 3; k++) y[w*3+k] += bc[k] * g[w];
    }
#pragma unroll
    for (int w = 0; w < 8; w++)
#pragma unroll
      for (int k = 0; k < 3; k++) atomicAdd(&UPD[(64+(w0+w)*3+k)*NN + n], y[w*3+k]);
  } else if (sy < 10) {               // (0,2,2)
    int w0 = (sy-8) * 8;
    float y[40];
#pragma unroll
    for (int q = 0; q < 40; q++) y[q] = 0.f;
    for (int v = 0; v < 16; v++) {
      float b[5];
#pragma unroll
      for (int j = 0; j < 5; j++) b[j] = AGT[(160+v*5+j)*NN+n];
      float bc[5];
#pragma unroll
      for (int k = 0; k < 5; k++) {
        float t = 0.f;
#pragma unroll
        for (int j = 0; j < 5; j++) t += b[j] * C.c022[j*5+k];
        bc[k] = t;
      }
      float g[8];
#pragma unroll
      for (int w = 0; w < 8; w++) g[w] = 0.f;
      for (int u = 0; u < 64; u++) {
        float au = HT[u*NN+n];
        const float* Wp = W + 327680 + (u*16+v)*16 + w0;
#pragma unroll
        for (int w = 0; w < 8; w++) g[w] += au * Wp[w];
      }
#pragma unroll
      for (int w = 0; w < 8; w++)
#pragma unroll
        for (int k = 0; k < 5; k++) y[w*5+k] += bc[k] * g[w];
    }
#pragma unroll
    for (int w = 0; w < 8; w++)
#pragma unroll
      for (int k = 0; k < 5; k++) atomicAdd(&UPD[(160+(w0+w)*5+k)*NN + n], y[w*5+k]);
  } else if (sy < 14) {               // (1,0,1)
    int w0 = (sy-10) * 8;
    float y[24];
#pragma unroll
    for (int q = 0; q < 24; q++) y[q] = 0.f;
    for (int u = 0; u < 32; u++) {
      float a0 = HT[(64+u*3+0)*NN+n], a1 = HT[(64+u*3+1)*NN+n], a2 = HT[(64+u*3+2)*NN+n];
      float ac[3];
#pragma unroll
      for (int k = 0; k < 3; k++) ac[k] = a0*C.c101[k] + a1*C.c101[3+k] + a2*C.c101[6+k];
      float g[8];
#pragma unroll
      for (int w = 0; w < 8; w++) g[w] = 0.f;
      for (int v = 0; v < 64; v++) {
        float bv = AGT[v*NN+n];
        const float* Wp = W + 344064 + (u*64+v)*32 + w0;
#pragma unroll
        for (int w = 0; w < 8; w++) g[w] += bv * Wp[w];
      }
#pragma unroll
      for (int w = 0; w < 8; w++)
#pragma unroll
        for (int k = 0; k < 3; k++) y[w*3+k] += ac[k] * g[w];
    }
#pragma unroll
    for (int w = 0; w < 8; w++)
#pragma unroll
      for (int k = 0; k < 3; k++) atomicAdd(&UPD[(64+(w0+w)*3+k)*NN + n], y[w*3+k]);
  } else {                            // (2,0,2)
    int w0 = (sy-14) * 8;
    float y[40];
#pragma unroll
    for (int q = 0; q < 40; q++) y[q] = 0.f;
    for (int u = 0; u < 16; u++) {
      float a[5];
#pragma unroll
      for (int i = 0; i < 5; i++) a[i] = HT[(160+u*5+i)*NN+n];
      float ac[5];
#pragma unroll
      for (int k = 0; k < 5; k++) {
        float t = 0.f;
#pragma unroll
        for (int i = 0; i < 5; i++) t += a[i] * C.c202[i*5+k];
        ac[k] = t;
      }
      float g[8];
#pragma unroll
      for (int w = 0; w < 8; w++) g[w] = 0.f;
      for (int v = 0; v < 64; v++) {
        float bv = AGT[v*NN+n];
        const float* Wp = W + 507904 + (u*64+v)*16 + w0;
#pragma unroll
        for (int w = 0; w < 8; w++) g[w] += bv * Wp[w];
      }
#pragma unroll
      for (int w = 0; w < 8; w++)
#pragma unroll
        for (int k = 0; k < 5; k++) y[w*5+k] += ac[k] * g[w];
    }
#pragma unroll
    for (int w = 0; w < 8; w++)
#pragma unroll
      for (int k = 0; k < 5; k++) atomicAdd(&UPD[(160+(w0+w)*5+k)*NN + n], y[w*5+k]);
  }
}

// update TP, scalar-output paths: (110),(220)
__global__ __launch_bounds__(64) void k_upd_d(
    const float* __restrict__ HT, const float* __restrict__ AGT,
    const float* __restrict__ W, CUpdD C, float* __restrict__ UPD) {
  int n = blockIdx.x * 64 + threadIdx.x;
  if (n >= NN) return;
  int sy = blockIdx.y;
  if (sy < 4) {                       // (1,1,0)
    int w0 = sy * 16;
    float y[16];
#pragma unroll
    for (int w = 0; w < 16; w++) y[w] = 0.f;
    for (int v = 0; v < 32; v++) {
      float b0 = AGT[(64+v*3+0)*NN+n], b1 = AGT[(64+v*3+1)*NN+n], b2 = AGT[(64+v*3+2)*NN+n];
      float bt[3];
#pragma unroll
      for (int i = 0; i < 3; i++) bt[i] = C.c110[i*3+0]*b0 + C.c110[i*3+1]*b1 + C.c110[i*3+2]*b2;
      for (int u = 0; u < 32; u++) {
        float D = HT[(64+u*3+0)*NN+n]*bt[0] + HT[(64+u*3+1)*NN+n]*bt[1] + HT[(64+u*3+2)*NN+n]*bt[2];
        const float* Wp = W + 409600 + (u*32+v)*64 + w0;
#pragma unroll
        for (int w = 0; w < 16; w++) y[w] += D * Wp[w];
      }
    }
#pragma unroll
    for (int w = 0; w < 16; w++) atomicAdd(&UPD[(w0+w)*NN + n], y[w]);
  } else {                            // (2,2,0)
    int w0 = (sy-4) * 16;
    float y[16];
#pragma unroll
    for (int w = 0; w < 16; w++) y[w] = 0.f;
    for (int v = 0; v < 16; v++) {
      float b[5];
#pragma unroll
      for (int j = 0; j < 5; j++) b[j] = AGT[(160+v*5+j)*NN+n];
      float bt[5];
#pragma unroll
      for (int i = 0; i < 5; i++) {
        float t = 0.f;
#pragma unroll
        for (int j = 0; j < 5; j++) t += C.c220[i*5+j] * b[j];
        bt[i] = t;
      }
      for (int u = 0; u < 16; u++) {
        float D = 0.f;
#pragma unroll
        for (int i = 0; i < 5; i++) D += HT[(160+u*5+i)*NN+n] * bt[i];
        const float* Wp = W + 540672 + (u*16+v)*64 + w0;
#pragma unroll
        for (int w = 0; w < 16; w++) y[w] += D * Wp[w];
      }
    }
#pragma unroll
    for (int w = 0; w < 16; w++) atomicAdd(&UPD[(w0+w)*NN + n], y[w]);
  }
}

// update TP, vector-vector paths: (112),(121),(211),(222)
__global__ __launch_bounds__(64) void k_upd_p(
    const float* __restrict__ HT, const float* __restrict__ AGT,
    const float* __restrict__ W, CUpdP C, float* __restrict__ UPD) {
  int n = blockIdx.x * 64 + threadIdx.x;
  if (n >= NN) return;
  int sy = blockIdx.y;
  if (sy == 0) {                      // (1,1,2)
    float y[80];
#pragma unroll
    for (int q = 0; q < 80; q++) y[q] = 0.f;
    for (int v = 0; v < 32; v++) {
      float b0 = AGT[(64+v*3+0)*NN+n], b1 = AGT[(64+v*3+1)*NN+n], b2 = AGT[(64+v*3+2)*NN+n];
      float bt[15];
#pragma unroll
      for (int i = 0; i < 3; i++)
#pragma unroll
        for (int k = 0; k < 5; k++)
          bt[i*5+k] = b0*C.c112[(i*3+0)*5+k] + b1*C.c112[(i*3+1)*5+k] + b2*C.c112[(i*3+2)*5+k];
      for (int u = 0; u < 32; u++) {
        float a0 = HT[(64+u*3+0)*NN+n], a1 = HT[(64+u*3+1)*NN+n], a2 = HT[(64+u*3+2)*NN+n];
        float P[5];
#pragma unroll
        for (int k = 0; k < 5; k++) P[k] = a0*bt[k] + a1*bt[5+k] + a2*bt[10+k];
        const float* Wp = W + 475136 + (u*32+v)*16;
#pragma unroll
        for (int w = 0; w < 16; w++) {
          float wv = Wp[w];
#pragma unroll
          for (int k = 0; k < 5; k++) y[w*5+k] += P[k] * wv;
        }
      }
    }
#pragma unroll
    for (int w = 0; w < 16; w++)
#pragma unroll
      for (int k = 0; k < 5; k++) atomicAdd(&UPD[(160+w*5+k)*NN + n], y[w*5+k]);
  } else if (sy == 1) {               // (1,2,1)
    float y[96];
#pragma unroll
    for (int q = 0; q < 96; q++) y[q] = 0.f;
    for (int v = 0; v < 16; v++) {
      float b[5];
#pragma unroll
      for (int j = 0; j < 5; j++) b[j] = AGT[(160+v*5+j)*NN+n];
      float bt[9];
#pragma unroll
      for (int i = 0; i < 3; i++)
#pragma unroll
        for (int k = 0; k < 3; k++) {
          float t = 0.f;
#pragma unroll
          for (int j = 0; j < 5; j++) t += b[j] * C.c121[(i*5+j)*3+k];
          bt[i*3+k] = t;
        }
      for (int u = 0; u < 32; u++) {
        float a0 = HT[(64+u*3+0)*NN+n], a1 = HT[(64+u*3+1)*NN+n], a2 = HT[(64+u*3+2)*NN+n];
        float P[3];
#pragma unroll
        for (int k = 0; k < 3; k++) P[k] = a0*bt[k] + a1*bt[3+k] + a2*bt[6+k];
        const float* Wp = W + 491520 + (u*16+v)*32;
#pragma unroll
        for (int w = 0; w < 32; w++) {
          float wv = Wp[w];
#pragma unroll
          for (int k = 0; k < 3; k++) y[w*3+k] += P[k] * wv;
        }
      }
    }
#pragma unroll
    for (int w = 0; w < 32; w++)
#pragma unroll
      for (int k = 0; k < 3; k++) atomicAdd(&UPD[(64+w*3+k)*NN + n], y[w*3+k]);
  } else if (sy == 2) {               // (2,1,1)
    float y[96];
#pragma unroll
    for (int q = 0; q < 96; q++) y[q] = 0.f;
    for (int v = 0; v < 32; v++) {
      float b0 = AGT[(64+v*3+0)*NN+n], b1 = AGT[(64+v*3+1)*NN+n], b2 = AGT[(64+v*3+2)*NN+n];
      float bt[15];
#pragma unroll
      for (int i = 0; i < 5; i++)
#pragma unroll
        for (int k = 0; k < 3; k++)
          bt[i*3+k] = b0*C.c211[(i*3+0)*3+k] + b1*C.c211[(i*3+1)*3+k] + b2*C.c211[(i*3+2)*3+k];
      for (int u = 0; u < 16; u++) {
        float a[5];
#pragma unroll
        for (int i = 0; i < 5; i++) a[i] = HT[(160+u*5+i)*NN+n];
        float P[3];
#pragma unroll
        for (int k = 0; k < 3; k++) {
          float t = 0.f;
#pragma unroll
          for (int i = 0; i < 5; i++) t += a[i] * bt[i*3+k];
          P[k] = t;
        }
        const float* Wp = W + 524288 + (u*32+v)*32;
#pragma unroll
        for (int w = 0; w < 32; w++) {
          float wv = Wp[w];
#pragma unroll
          for (int k = 0; k < 3; k++) y[w*3+k] += P[k] * wv;
        }
      }
    }
#pragma unroll
    for (int w = 0; w < 32; w++)
#pragma unroll
      for (int k = 0; k < 3; k++) atomicAdd(&UPD[(64+w*3+k)*NN + n], y[w*3+k]);
  } else {                            // (2,2,2)
    float y[80];
#pragma unroll
    for (int q = 0; q < 80; q++) y[q] = 0.f;
    for (int v = 0; v < 16; v++) {
      float b[5];
#pragma unroll
      for (int j = 0; j < 5; j++) b[j] = AGT[(160+v*5+j)*NN+n];
      float bt[25];
#pragma unroll
      for (int i = 0; i < 5; i++)
#pragma unroll
        for (int k = 0; k < 5; k++) {
          float t = 0.f;
#pragma unroll
          for (int j = 0; j < 5; j++) t += b[j] * C.c222[(i*5+j)*5+k];
          bt[i*5+k] = t;
        }
      for (int u = 0; u < 16; u++) {
        float a[5];
#pragma unroll
        for (int i = 0; i < 5; i++) a[i] = HT[(160+u*5+i)*NN+n];
        float P[5];
#pragma unroll
        for (int k = 0; k < 5; k++) {
          float t = 0.f;
#pragma unroll
          for (int i = 0; i < 5; i++) t += a[i] * bt[i*5+k];
          P[k] = t;
        }
        const float* Wp = W + 557056 + (u*16+v)*16;
#pragma unroll
        for (int w = 0; w < 16; w++) {
          float wv = Wp[w];
#pragma unroll
          for (int k = 0; k < 5; k++) y[w*5+k] += P[k] * wv;
        }
      }
    }
#pragma unroll
    for (int w = 0; w < 16; w++)
#pragma unroll
      for (int k = 0; k < 5; k++) atomicAdd(&UPD[(160+w*5+k)*NN + n], y[w*5+k]);
  }
}

// h_new = h + upd_tp + lin_upd(h)
__global__ __launch_bounds__(256) void k_apply(
    const float* __restrict__ Hsrc, const float* __restrict__ UPD,
    const float* __restrict__ Wl, float* __restrict__ Hdst) {
  int n = blockIdx.x * 256 + threadIdx.x;
  int e = blockIdx.y;
  if (n >= NN) return;
  float lin = 0.f;
  if (e < 64) {
    for (int u = 0; u < 64; u++) lin += Hsrc[u*NN+n] * Wl[u*64+e];
    lin *= 0.125f;
  } else if (e < 160) {
    int t = e - 64, v = t/3, i = t - v*3;
    for (int u = 0; u < 32; u++) lin += Hsrc[(64+u*3+i)*NN+n] * Wl[4096 + u*32+v];
    lin *= 0.17677669529663687f;
  } else {
    int t = e - 160, v = t/5, i = t - v*5;
    for (int u = 0; u < 16; u++) lin += Hsrc[(160+u*5+i)*NN+n] * Wl[5120 + u*16+v];
    lin *= 0.25f;
  }
  Hdst[e*NN + n] = Hsrc[e*NN + n] + UPD[e*NN + n] + lin;
}

__global__ __launch_bounds__(256) void k_cnt(const int* __restrict__ batch, float* __restrict__ CNT) {
  int n = blockIdx.x * 256 + threadIdx.x;
  if (n >= NN) return;
  atomicAdd(&CNT[batch[n]], 1.0f);
}

__global__ __launch_bounds__(256) void k_pool(
    const float* __restrict__ HT, const int* __restrict__ batch, float* __restrict__ POOL) {
  int n = blockIdx.x * 256 + threadIdx.x;
  int w = blockIdx.y;
  if (n >= NN) return;
  atomicAdd(&POOL[batch[n]*64 + w], HT[w*NN + n]);
}

__global__ __launch_bounds__(256) void k_out(
    const float* __restrict__ POOL, const float* __restrict__ CNT,
    const float* __restrict__ wf, float* __restrict__ out) {
  int tid = blockIdx.x * 256 + threadIdx.x;
  if (tid >= NG * 128) return;
  int g = tid >> 7, d = tid & 127;
  float inv = 1.0f / fmaxf(CNT[g], 1.0f);
  float acc = 0.f;
  for (int w = 0; w < 64; w++) acc += POOL[g*64 + w] * wf[w*128 + d];
  out[tid] = acc * inv * 0.125f;
}

// ---------------- host-side real Wigner-3j (mirrors the reference) ----------------
typedef std::complex<double> cd;
static double hfact(int nn) { double f = 1; for (int i = 2; i <= nn; i++) f *= i; return f; }
static double hcg(int j1,int m1,int j2,int m2,int j3,int m3) {
  if (m1 + m2 != m3) return 0.0;
  double pre = sqrt((2*j3+1) * hfact(j3+j1-j2) * hfact(j3-j1+j2) * hfact(j1+j2-j3) / hfact(j1+j2+j3+1));
  pre *= sqrt(hfact(j3+m3)*hfact(j3-m3)*hfact(j1-m1)*hfact(j1+m1)*hfact(j2-m2)*hfact(j2+m2));
  double s = 0;
  for (int k = 0; k <= j1+j2-j3; k++) {
    int a1=j1+j2-j3-k, a2=j1-m1-k, a3=j2+m2-k, a4=j3-j2+m1+k, a5=j3-j1-m2+k;
    if (a1<0||a2<0||a3<0||a4<0||a5<0) continue;
    s += ((k&1)?-1.0:1.0) / (hfact(k)*hfact(a1)*hfact(a2)*hfact(a3)*hfact(a4)*hfact(a5));
  }
  return pre * s;
}
static void hA(int l, cd A[5][5]) {
  for (int r = 0; r < 5; r++) for (int c = 0; c < 5; c++) A[r][c] = cd(0,0);
  A[l][l] = cd(1,0);
  for (int m = 1; m <= l; m++) {
    double sg = (m & 1) ? -1.0 : 1.0;
    A[l+m][l+m] = cd(sg/sqrt(2.0), 0);
    A[l+m][l-m] = cd(1.0/sqrt(2.0), 0);
    A[l-m][l+m] = cd(0, -sg/sqrt(2.0));
    A[l-m][l-m] = cd(0, 1.0/sqrt(2.0));
  }
}
static void hw3j(int l1, int l2, int l3, double* out) {
  int n1 = 2*l1+1, n2 = 2*l2+1, n3 = 2*l3+1;
  double Wc[5][5][5]; memset(Wc, 0, sizeof Wc);
  for (int m1 = -l1; m1 <= l1; m1++) for (int m2 = -l2; m2 <= l2; m2++) {
    int m3 = -(m1+m2);
    if (m3 < -l3 || m3 > l3) continue;
    int ex = l1 - l2 - m3;
    double sg = (ex % 2 == 0) ? 1.0 : -1.0;
    Wc[m1+l1][m2+l2][m3+l3] = sg / sqrt((double)(2*l3+1)) * hcg(l1,m1,l2,m2,l3,-m3);
  }
  cd A1[5][5], A2[5][5], A3[5][5];
  hA(l1,A1); hA(l2,A2); hA(l3,A3);
  double nrm = 0;
  for (int a = 0; a < n1; a++) for (int b = 0; b < n2; b++) for (int c = 0; c < n3; c++) {
    cd acc(0,0);
    for (int d = 0; d < n1; d++) for (int e = 0; e < n2; e++) for (int f = 0; f < n3; f++) {
      double w = Wc[d][e][f];
      if (w == 0.0) continue;
      acc += A1[a][d] * A2[b][e] * A3[c][f] * w;
    }
    out[(a*n2+b)*n3+c] = acc.real();
    nrm += acc.real() * acc.real();
  }
  nrm = sqrt(nrm);
  for (int i = 0; i < n1*n2*n3; i++) out[i] /= nrm;
}

// ---------------- launch ----------------
extern "C" void kernel_launch(void* const* d_in, const int* in_sizes, int n_in,
                              void* d_out, int out_size, void* d_ws, size_t ws_size,
                              hipStream_t stream) {
  const float* x        = (const float*)d_in[0];
  const float* pos      = (const float*)d_in[1];
  const float* w_init   = (const float*)d_in[2];
  const float* w_tp_msg = (const float*)d_in[3];
  const float* w_lin_msg= (const float*)d_in[4];
  const float* w_tp_upd = (const float*)d_in[5];
  const float* w_lin_upd= (const float*)d_in[6];
  const float* w_final  = (const float*)d_in[7];
  const int*   ei       = (const int*)d_in[8];
  const int*   batch    = (const int*)d_in[9];
  float* out = (float*)d_out;
  float* ws  = (float*)d_ws;

  // workspace layout (floats)
  float* EA     = ws;                      // 640000
  float* CN     = EA + 640000;             // 5760000
  float* HTA    = CN + 5760000;            // 2400000
  float* HTB    = HTA + 2400000;           // 2400000
  float* Z      = HTB + 2400000;           // 9120000
  float* AGG_NM = Z + 9120000;             // 2400000
  float* UPD_T  = AGG_NM + 2400000;        // 2400000 (contiguous with AGG_NM for one memset)
  float* AGG_T  = UPD_T + 2400000;         // 2400000
  float* POOL   = AGG_T + 2400000;         // 4096
  float* CNT    = POOL + 4096;             // 64

  // ---- host: compute real-w3j tensors and fill coefficient structs ----
  double C000d[1], C011d[9], C101d[9], C110d[9], C112d[45], C022d[25],
         C202d[25], C121d[45], C211d[45], C220d[25], C222d[125];
  hw3j(0,0,0,C000d); hw3j(0,1,1,C011d); hw3j(1,0,1,C101d); hw3j(1,1,0,C110d);
  hw3j(1,1,2,C112d); hw3j(0,2,2,C022d); hw3j(2,0,2,C202d); hw3j(1,2,1,C121d);
  hw3j(2,1,1,C211d); hw3j(2,2,0,C220d); hw3j(2,2,2,C222d);

  CMsgPre cmsg;
  cmsg.a000 = (float)(C000d[0] / sqrt(128.0));
  cmsg.a011 = (float)(1.0 / sqrt(192.0));
  cmsg.a110 = (float)(1.0 / sqrt(64.0));
  cmsg.a112 = (float)(1.0 / sqrt(64.0));
  cmsg.a211 = (float)(1.0 / sqrt(48.0));
  for (int i = 0; i < 9;  i++) cmsg.c101[i] = (float)(C101d[i] / sqrt(96.0));
  for (int i = 0; i < 25; i++) cmsg.c202[i] = (float)(C202d[i] / sqrt(32.0));

  CEdge ce;
  for (int i = 0; i < 9;  i++) ce.c011[i] = (float)C011d[i];
  for (int i = 0; i < 9;  i++) ce.c110[i] = (float)C110d[i];
  for (int i = 0; i < 45; i++) ce.c112[i] = (float)C112d[i];
  for (int i = 0; i < 45; i++) ce.c211[i] = (float)C211d[i];

  CUpdS cus;
  cus.s000 = (float)(C000d[0] / sqrt(64.0*64.0*3.0));
  for (int i = 0; i < 9;  i++) cus.c011[i] = (float)(C011d[i] / sqrt(64.0*32.0*4.0));
  for (int i = 0; i < 25; i++) cus.c022[i] = (float)(C022d[i] / sqrt(64.0*16.0*4.0));
  for (int i = 0; i < 9;  i++) cus.c101[i] = (float)(C101d[i] / sqrt(32.0*64.0*4.0));
  for (int i = 0; i < 25; i++) cus.c202[i] = (float)(C202d[i] / sqrt(16.0*64.0*4.0));

  CUpdD cud;
  for (int i = 0; i < 9;  i++) cud.c110[i] = (float)(C110d[i] / sqrt(32.0*32.0*3.0));
  for (int i = 0; i < 25; i++) cud.c220[i] = (float)(C220d[i] / sqrt(16.0*16.0*3.0));

  CUpdP cup;
  for (int i = 0; i < 45;  i++) cup.c112[i] = (float)(C112d[i] / sqrt(32.0*32.0*4.0));
  for (int i = 0; i < 45;  i++) cup.c121[i] = (float)(C121d[i] / sqrt(32.0*16.0*4.0));
  for (int i = 0; i < 45;  i++) cup.c211[i] = (float)(C211d[i] / sqrt(16.0*32.0*4.0));
  for (int i = 0; i < 125; i++) cup.c222[i] = (float)(C222d[i] / sqrt(16.0*16.0*4.0));

  // ---- launches ----
  k_edge_attr<<<(NE+255)/256, 256, 0, stream>>>(pos, ei, ce, EA, CN);
  k_h_init<<<dim3(40, HD), 256, 0, stream>>>(x, w_init, HTA);

  float* cur = HTA;
  float* nxt = HTB;
  for (int L = 0; L < 6; L++) {
    hipMemsetAsync(AGG_NM, 0, (size_t)4800000 * sizeof(float), stream); // AGG_NM + UPD_T
    k_node_pre<<<dim3(40, ZD), 256, 0, stream>>>(cur, w_tp_msg + (size_t)L*MSG_WS,
                                                 w_lin_msg + (size_t)L*LIN_WS, cmsg, Z);
    k_edge<<<1280, 256, 0, stream>>>(ei, EA, CN, Z, AGG_NM);
    k_transpose<<<dim3(40, HD), 256, 0, stream>>>(AGG_NM, AGG_T);
    const float* Wu = w_tp_upd + (size_t)L*UPD_WS;
    k_upd_s<<<dim3(157, 16), 64, 0, stream>>>(cur, AGG_T, Wu, cus, UPD_T);
    k_upd_d<<<dim3(157, 8),  64, 0, stream>>>(cur, AGG_T, Wu, cud, UPD_T);
    k_upd_p<<<dim3(157, 4),  64, 0, stream>>>(cur, AGG_T, Wu, cup, UPD_T);
    k_apply<<<dim3(40, HD), 256, 0, stream>>>(cur, UPD_T, w_lin_upd + (size_t)L*LIN_WS, nxt);
    float* tmp = cur; cur = nxt; nxt = tmp;
  }

  hipMemsetAsync(POOL, 0, (size_t)(4096 + 64) * sizeof(float), stream);
  k_cnt<<<(NN+255)/256, 256, 0, stream>>>(batch, CNT);
  k_pool<<<dim3(40, 64), 256, 0, stream>>>(cur, batch, POOL);
  k_out<<<32, 256, 0, stream>>>(POOL, CNT, w_final, out);
}

// Round 2
// 5520.888 us; speedup vs baseline: 1.4825x; 1.4825x over previous
//
#include <hip/hip_runtime.h>
#include <cmath>
#include <cstring>
#include <complex>

#define NN 10000
#define NE 160000
#define HD 240
#define ZD 912
#define NG 64
#define MSG_WS 10496
#define UPD_WS 561152
#define LIN_WS 5376

// ---------------- kernarg coefficient structs ----------------
struct CMsgPre { float a000, a011, a110, a112, a211; float c101[9]; float c202[25]; };
struct CEdge   { float c011[9]; float c110[9]; float c112[45]; float c211[45]; };
struct CUpdS   { float s000; float c011[9]; float c022[25]; float c101[9]; float c202[25]; };
struct CUpdD   { float c110[9]; float c220[25]; };
struct CUpdP   { float c112[45]; float c121[45]; float c211[45]; float c222[125]; };

// ---------------- kernels ----------------

// per-edge: dist, unit vec, and the 36 w3j·n contraction values
__global__ __launch_bounds__(256) void k_edge_attr(
    const float* __restrict__ pos, const int* __restrict__ ei, CEdge C,
    float* __restrict__ EA, float* __restrict__ CN) {
  int e = blockIdx.x * 256 + threadIdx.x;
  if (e >= NE) return;
  int r = ei[e], c = ei[NE + e];
  float dx = pos[r*3+0] - pos[c*3+0];
  float dy = pos[r*3+1] - pos[c*3+1];
  float dz = pos[r*3+2] - pos[c*3+2];
  float d = sqrtf(dx*dx + dy*dy + dz*dz);
  float inv = 1.0f / fmaxf(d, 1e-8f);
  float n0 = dx*inv, n1 = dy*inv, n2 = dz*inv;
  EA[e*4+0] = d; EA[e*4+1] = n0; EA[e*4+2] = n1; EA[e*4+3] = n2;
  float* cn = CN + (size_t)e*36;
#pragma unroll
  for (int k = 0; k < 3; k++)
    cn[k] = n0*C.c011[0*3+k] + n1*C.c011[1*3+k] + n2*C.c011[2*3+k];
#pragma unroll
  for (int i = 0; i < 3; i++)
    cn[3+i] = n0*C.c110[i*3+0] + n1*C.c110[i*3+1] + n2*C.c110[i*3+2];
#pragma unroll
  for (int i = 0; i < 3; i++)
#pragma unroll
    for (int k = 0; k < 5; k++)
      cn[6+i*5+k] = n0*C.c112[(i*3+0)*5+k] + n1*C.c112[(i*3+1)*5+k] + n2*C.c112[(i*3+2)*5+k];
#pragma unroll
  for (int i = 0; i < 5; i++)
#pragma unroll
    for (int k = 0; k < 3; k++)
      cn[21+i*3+k] = n0*C.c211[(i*3+0)*3+k] + n1*C.c211[(i*3+1)*3+k] + n2*C.c211[(i*3+2)*3+k];
}

// h init: elem-major H[e][n]
__global__ __launch_bounds__(256) void k_h_init(
    const float* __restrict__ x, const float* __restrict__ wi, float* __restrict__ HT) {
  int n = blockIdx.x * 256 + threadIdx.x;
  int e = blockIdx.y;
  if (n >= NN) return;
  float v = 0.f;
  if (e < 64)
    v = (x[n*3+0]*wi[0*64+e] + x[n*3+1]*wi[64+e] + x[n*3+2]*wi[128+e]) * 0.57735026918962576f;
  HT[e*NN + n] = v;
}

// per-node msg precompute: z fragments (672) + msg-linear (240) -> Z[n][912] (node-major)
__global__ __launch_bounds__(256) void k_node_pre(
    const float* __restrict__ HT, const float* __restrict__ Wm, const float* __restrict__ Wl,
    CMsgPre C, float* __restrict__ Z) {
  int n = blockIdx.x * 256 + threadIdx.x;
  int widx = blockIdx.y;
  if (n >= NN) return;
  float acc = 0.f;
  if (widx < 64) {
    int w = widx;
    for (int u = 0; u < 64; u++) acc += HT[u*NN+n] * Wm[u*64+w];
    acc *= C.a000;
  } else if (widx < 96) {
    int w = widx - 64;
    for (int u = 0; u < 64; u++) acc += HT[u*NN+n] * Wm[4096 + u*32+w];
    acc *= C.a011;
  } else if (widx < 192) {
    int t = widx - 96, w = t/3, k = t - w*3;
    for (int u = 0; u < 32; u++) {
      float g = HT[(64+u*3+0)*NN+n]*C.c101[0*3+k]
              + HT[(64+u*3+1)*NN+n]*C.c101[1*3+k]
              + HT[(64+u*3+2)*NN+n]*C.c101[2*3+k];
      acc += Wm[6144 + u*32+w] * g;
    }
  } else if (widx < 384) {
    int t = widx - 192, w = t/3, i = t - w*3;
    for (int u = 0; u < 32; u++) acc += HT[(64+u*3+i)*NN+n] * Wm[7168 + u*64+w];
    acc *= C.a110;
  } else if (widx < 432) {
    int t = widx - 384, w = t/3, i = t - w*3;
    for (int u = 0; u < 32; u++) acc += HT[(64+u*3+i)*NN+n] * Wm[9216 + u*16+w];
    acc *= C.a112;
  } else if (widx < 512) {
    int t = widx - 432, w = t/5, k = t - w*5;
    for (int u = 0; u < 16; u++) {
      float g = 0.f;
#pragma unroll
      for (int i = 0; i < 5; i++) g += HT[(160+u*5+i)*NN+n] * C.c202[i*5+k];
      acc += Wm[9728 + u*16+w] * g;
    }
  } else if (widx < 672) {
    int t = widx - 512, w = t/5, i = t - w*5;
    for (int u = 0; u < 16; u++) acc += HT[(160+u*5+i)*NN+n] * Wm[9984 + u*32+w];
    acc *= C.a211;
  } else {
    int e2 = widx - 672;
    if (e2 < 64) {
      for (int u = 0; u < 64; u++) acc += HT[u*NN+n] * Wl[u*64+e2];
      acc *= 0.125f;
    } else if (e2 < 160) {
      int t = e2 - 64, v = t/3, i = t - v*3;
      for (int u = 0; u < 32; u++) acc += HT[(64+u*3+i)*NN+n] * Wl[4096 + u*32+v];
      acc *= 0.17677669529663687f;
    } else {
      int t = e2 - 160, v = t/5, i = t - v*5;
      for (int u = 0; u < 16; u++) acc += HT[(160+u*5+i)*NN+n] * Wl[5120 + u*16+v];
      acc *= 0.25f;
    }
  }
  Z[(size_t)n*ZD + widx] = acc;
}

// per-edge combine + scatter. one wave per edge, LDS-staged z record of col.
__global__ __launch_bounds__(256) void k_edge(
    const int* __restrict__ ei, const float* __restrict__ EA, const float* __restrict__ CN,
    const float* __restrict__ Z, float* __restrict__ AGG) {
  __shared__ float zsh[4][ZD];
  int lane = threadIdx.x & 63, wid = threadIdx.x >> 6;
  int wg = blockIdx.x * 4 + wid;
  int stride = gridDim.x * 4;
  int iters = (NE + stride - 1) / stride;
  for (int it = 0; it < iters; ++it) {
    int e = wg + it * stride;
    bool act = e < NE;
    int r = 0;
    float s = 0.f;
    const float* cn = CN;
    if (act) {
      r = ei[e];
      int c = ei[NE + e];
      s = EA[e*4];
      cn = CN + (size_t)e*36;
      const float* zr = Z + (size_t)c*ZD;
      for (int t = lane; t < ZD; t += 64) zsh[wid][t] = zr[t];
    }
    __syncthreads();
    if (act) {
      const float* z = zsh[wid];
#pragma unroll
      for (int j = 0; j < 4; j++) {
        int idx = lane + 64*j;
        if (idx < HD) {
          float y = z[672 + idx];  // msg-linear part
          if (idx < 64) {
            int w = idx;
            y += s * z[w];
#pragma unroll
            for (int i = 0; i < 3; i++) y += z[192 + w*3 + i] * cn[3+i];
          } else if (idx < 160) {
            int t = idx - 64, w = t/3, k = t - w*3;
            y += cn[k] * z[64 + w] + s * z[96 + t];
#pragma unroll
            for (int i = 0; i < 5; i++) y += z[512 + w*5 + i] * cn[21 + i*3 + k];
          } else {
            int t = idx - 160, w = t/5, k = t - w*5;
            y += s * z[432 + t];
#pragma unroll
            for (int i = 0; i < 3; i++) y += z[384 + w*3 + i] * cn[6 + i*5 + k];
          }
          atomicAdd(&AGG[(size_t)r*HD + idx], y);
        }
      }
    }
    __syncthreads();
  }
}

// transpose AGG node-major -> elem-major
__global__ __launch_bounds__(256) void k_transpose(
    const float* __restrict__ A_nm, float* __restrict__ A_t) {
  int n = blockIdx.x * 256 + threadIdx.x;
  int e = blockIdx.y;
  if (n >= NN) return;
  A_t[e*NN + n] = A_nm[(size_t)n*HD + e];
}

// ---------- unified update-TP kernel ----------
// grid = (40, 12): py 0-3 -> l=0 outputs (w-chunks of 16); py 4-7 -> l=1 (w-chunks of 8);
// py 8-11 -> l=2 (w-chunks of 4). Each piece writes its output slice exactly once.
// Weights staged through 16KB LDS chunks; inner loops read weights as uniform LDS broadcasts.
__global__ __launch_bounds__(256) void k_upd(
    const float* __restrict__ A,   // HT  (h, elem-major)
    const float* __restrict__ B,   // AGT (agg, elem-major)
    const float* __restrict__ W,
    CUpdS CS, CUpdD CD, CUpdP CP,
    float* __restrict__ UPD) {
  __shared__ float lds[4096];
  int tid = threadIdx.x;
  int n = blockIdx.x * 256 + tid;
  bool act = n < NN;
  int nc = act ? n : NN - 1;
  int py = blockIdx.y;

  if (py < 4) {
    // ================= l=0 output block: paths (000),(110),(220) =================
    int w0 = py * 16;
    float y[16];
#pragma unroll
    for (int w = 0; w < 16; w++) y[w] = 0.f;

    // ---- (0,0,0): W[u64][v64][w64] @0
    for (int c = 0; c < 16; ++c) {
      __syncthreads();
      for (int t = tid; t < 4096; t += 256) {
        int u2 = t >> 10, v = (t >> 4) & 63, w = t & 15;
        lds[t] = W[(((c << 2) + u2) * 64 + v) * 64 + w0 + w];
      }
      __syncthreads();
      float ha[4];
#pragma unroll
      for (int u2 = 0; u2 < 4; u2++) ha[u2] = A[((c << 2) + u2) * NN + nc] * CS.s000;
#pragma unroll 2
      for (int v = 0; v < 64; ++v) {
        float bv = B[v * NN + nc];
#pragma unroll
        for (int u2 = 0; u2 < 4; u2++) {
          float p = ha[u2] * bv;
          const float* wl = lds + (u2 << 10) + (v << 4);
#pragma unroll
          for (int w = 0; w < 16; w++) y[w] += p * wl[w];
        }
      }
    }

    // ---- (1,1,0): W[u32][v32][w64] @409600
    for (int c = 0; c < 4; ++c) {
      __syncthreads();
      for (int t = tid; t < 4096; t += 256) {
        int u2 = t >> 9, v = (t >> 4) & 31, w = t & 15;
        lds[t] = W[409600 + ((c * 8 + u2) * 32 + v) * 64 + w0 + w];
      }
      __syncthreads();
      float a[8][3];
#pragma unroll
      for (int u2 = 0; u2 < 8; u2++)
#pragma unroll
        for (int i = 0; i < 3; i++) a[u2][i] = A[(64 + (c * 8 + u2) * 3 + i) * NN + nc];
#pragma unroll 2
      for (int v = 0; v < 32; ++v) {
        float b0 = B[(64 + v * 3 + 0) * NN + nc], b1 = B[(64 + v * 3 + 1) * NN + nc],
              b2 = B[(64 + v * 3 + 2) * NN + nc];
        float bt[3];
#pragma unroll
        for (int i = 0; i < 3; i++)
          bt[i] = CD.c110[i * 3 + 0] * b0 + CD.c110[i * 3 + 1] * b1 + CD.c110[i * 3 + 2] * b2;
#pragma unroll
        for (int u2 = 0; u2 < 8; u2++) {
          float D = a[u2][0] * bt[0] + a[u2][1] * bt[1] + a[u2][2] * bt[2];
          const float* wl = lds + u2 * 512 + v * 16;
#pragma unroll
          for (int w = 0; w < 16; w++) y[w] += D * wl[w];
        }
      }
    }

    // ---- (2,2,0): W[u16][v16][w64] @540672 (single stage)
    __syncthreads();
    for (int t = tid; t < 4096; t += 256) {
      int u = t >> 8, v = (t >> 4) & 15, w = t & 15;
      lds[t] = W[540672 + (u * 16 + v) * 64 + w0 + w];
    }
    __syncthreads();
    for (int ug = 0; ug < 2; ++ug) {
      float a[8][5];
#pragma unroll
      for (int u2 = 0; u2 < 8; u2++)
#pragma unroll
        for (int i = 0; i < 5; i++) a[u2][i] = A[(160 + (ug * 8 + u2) * 5 + i) * NN + nc];
      for (int v = 0; v < 16; ++v) {
        float b[5];
#pragma unroll
        for (int j = 0; j < 5; j++) b[j] = B[(160 + v * 5 + j) * NN + nc];
        float bt[5];
#pragma unroll
        for (int i = 0; i < 5; i++) {
          float t2 = 0.f;
#pragma unroll
          for (int j = 0; j < 5; j++) t2 += CD.c220[i * 5 + j] * b[j];
          bt[i] = t2;
        }
#pragma unroll
        for (int u2 = 0; u2 < 8; u2++) {
          float D = 0.f;
#pragma unroll
          for (int i = 0; i < 5; i++) D += a[u2][i] * bt[i];
          const float* wl = lds + (ug * 8 + u2) * 256 + v * 16;
#pragma unroll
          for (int w = 0; w < 16; w++) y[w] += D * wl[w];
        }
      }
    }

    if (act) {
#pragma unroll
      for (int w = 0; w < 16; w++) UPD[(w0 + w) * NN + nc] = y[w];
    }

  } else if (py < 8) {
    // ================= l=1 output block: paths (011),(101),(121),(211) =================
    int w0 = (py - 4) * 8;
    float y[24];
#pragma unroll
    for (int q = 0; q < 24; q++) y[q] = 0.f;

    // ---- (0,1,1): W[u64][v32][w32] @262144
    for (int c = 0; c < 4; ++c) {
      __syncthreads();
      for (int t = tid; t < 4096; t += 256) {
        int u2 = t >> 8, v = (t >> 3) & 31, w = t & 7;
        lds[t] = W[262144 + ((c * 16 + u2) * 32 + v) * 32 + w0 + w];
      }
      __syncthreads();
      float a[16];
#pragma unroll
      for (int u2 = 0; u2 < 16; u2++) a[u2] = A[(c * 16 + u2) * NN + nc];
#pragma unroll 2
      for (int v = 0; v < 32; ++v) {
        float b0 = B[(64 + v * 3 + 0) * NN + nc], b1 = B[(64 + v * 3 + 1) * NN + nc],
              b2 = B[(64 + v * 3 + 2) * NN + nc];
        float bc[3];
#pragma unroll
        for (int k = 0; k < 3; k++) bc[k] = b0 * CS.c011[k] + b1 * CS.c011[3 + k] + b2 * CS.c011[6 + k];
        float g8[8];
#pragma unroll
        for (int w = 0; w < 8; w++) g8[w] = 0.f;
#pragma unroll
        for (int u2 = 0; u2 < 16; u2++) {
          const float* wl = lds + u2 * 256 + v * 8;
#pragma unroll
          for (int w = 0; w < 8; w++) g8[w] += a[u2] * wl[w];
        }
#pragma unroll
        for (int w = 0; w < 8; w++)
#pragma unroll
          for (int k = 0; k < 3; k++) y[w * 3 + k] += bc[k] * g8[w];
      }
    }

    // ---- (1,0,1): W[u32][v64][w32] @344064
    for (int c = 0; c < 4; ++c) {
      __syncthreads();
      for (int t = tid; t < 4096; t += 256) {
        int u2 = t >> 9, v = (t >> 3) & 63, w = t & 7;
        lds[t] = W[344064 + ((c * 8 + u2) * 64 + v) * 32 + w0 + w];
      }
      __syncthreads();
      float ac[8][3];
#pragma unroll
      for (int u2 = 0; u2 < 8; u2++) {
        float a0 = A[(64 + (c * 8 + u2) * 3 + 0) * NN + nc];
        float a1 = A[(64 + (c * 8 + u2) * 3 + 1) * NN + nc];
        float a2 = A[(64 + (c * 8 + u2) * 3 + 2) * NN + nc];
#pragma unroll
        for (int k = 0; k < 3; k++)
          ac[u2][k] = a0 * CS.c101[k] + a1 * CS.c101[3 + k] + a2 * CS.c101[6 + k];
      }
      float g[8][8];
#pragma unroll
      for (int u2 = 0; u2 < 8; u2++)
#pragma unroll
        for (int w = 0; w < 8; w++) g[u2][w] = 0.f;
#pragma unroll 2
      for (int v = 0; v < 64; ++v) {
        float bv = B[v * NN + nc];
#pragma unroll
        for (int u2 = 0; u2 < 8; u2++) {
          const float* wl = lds + u2 * 512 + v * 8;
#pragma unroll
          for (int w = 0; w < 8; w++) g[u2][w] += bv * wl[w];
        }
      }
#pragma unroll
      for (int u2 = 0; u2 < 8; u2++)
#pragma unroll
        for (int w = 0; w < 8; w++)
#pragma unroll
          for (int k = 0; k < 3; k++) y[w * 3 + k] += ac[u2][k] * g[u2][w];
    }

    // ---- (1,2,1): W[u32][v16][w32] @491520 (single stage)
    __syncthreads();
    for (int t = tid; t < 4096; t += 256) {
      int u = t >> 7, v = (t >> 3) & 15, w = t & 7;
      lds[t] = W[491520 + (u * 16 + v) * 32 + w0 + w];
    }
    __syncthreads();
    for (int ug = 0; ug < 4; ++ug) {
      float a[8][3];
#pragma unroll
      for (int u2 = 0; u2 < 8; u2++)
#pragma unroll
        for (int i = 0; i < 3; i++) a[u2][i] = A[(64 + (ug * 8 + u2) * 3 + i) * NN + nc];
      for (int v = 0; v < 16; ++v) {
        float b[5];
#pragma unroll
        for (int j = 0; j < 5; j++) b[j] = B[(160 + v * 5 + j) * NN + nc];
        float bt[9];
#pragma unroll
        for (int i = 0; i < 3; i++)
#pragma unroll
          for (int k = 0; k < 3; k++) {
            float t2 = 0.f;
#pragma unroll
            for (int j = 0; j < 5; j++) t2 += b[j] * CP.c121[(i * 5 + j) * 3 + k];
            bt[i * 3 + k] = t2;
          }
#pragma unroll
        for (int u2 = 0; u2 < 8; u2++) {
          float P[3];
#pragma unroll
          for (int k = 0; k < 3; k++)
            P[k] = a[u2][0] * bt[k] + a[u2][1] * bt[3 + k] + a[u2][2] * bt[6 + k];
          const float* wl = lds + (ug * 8 + u2) * 128 + v * 8;
#pragma unroll
          for (int w = 0; w < 8; w++)
#pragma unroll
            for (int k = 0; k < 3; k++) y[w * 3 + k] += P[k] * wl[w];
        }
      }
    }

    // ---- (2,1,1): W[u16][v32][w32] @524288 (single stage)
    __syncthreads();
    for (int t = tid; t < 4096; t += 256) {
      int u = t >> 8, v = (t >> 3) & 31, w = t & 7;
      lds[t] = W[524288 + (u * 32 + v) * 32 + w0 + w];
    }
    __syncthreads();
    for (int ug = 0; ug < 2; ++ug) {
      float a[8][5];
#pragma unroll
      for (int u2 = 0; u2 < 8; u2++)
#pragma unroll
        for (int i = 0; i < 5; i++) a[u2][i] = A[(160 + (ug * 8 + u2) * 5 + i) * NN + nc];
#pragma unroll 2
      for (int v = 0; v < 32; ++v) {
        float b0 = B[(64 + v * 3 + 0) * NN + nc], b1 = B[(64 + v * 3 + 1) * NN + nc],
              b2 = B[(64 + v * 3 + 2) * NN + nc];
        float bt[15];
#pragma unroll
        for (int i = 0; i < 5; i++)
#pragma unroll
          for (int k = 0; k < 3; k++)
            bt[i * 3 + k] = b0 * CP.c211[(i * 3 + 0) * 3 + k] + b1 * CP.c211[(i * 3 + 1) * 3 + k] +
                            b2 * CP.c211[(i * 3 + 2) * 3 + k];
#pragma unroll
        for (int u2 = 0; u2 < 8; u2++) {
          float P[3];
#pragma unroll
          for (int k = 0; k < 3; k++) {
            float t2 = 0.f;
#pragma unroll
            for (int i = 0; i < 5; i++) t2 += a[u2][i] * bt[i * 3 + k];
            P[k] = t2;
          }
          const float* wl = lds + (ug * 8 + u2) * 256 + v * 8;
#pragma unroll
          for (int w = 0; w < 8; w++)
#pragma unroll
            for (int k = 0; k < 3; k++) y[w * 3 + k] += P[k] * wl[w];
        }
      }
    }

    if (act) {
#pragma unroll
      for (int w = 0; w < 8; w++)
#pragma unroll
        for (int k = 0; k < 3; k++) UPD[(64 + (w0 + w) * 3 + k) * NN + nc] = y[w * 3 + k];
    }

  } else {
    // ================= l=2 output block: paths (022),(202),(112),(222) =================
    int w0 = (py - 8) * 4;
    float y[20];
#pragma unroll
    for (int q = 0; q < 20; q++) y[q] = 0.f;

    // ---- (0,2,2): W[u64][v16][w16] @327680 (single stage)
    __syncthreads();
    for (int t = tid; t < 4096; t += 256) {
      int u = t >> 6, v = (t >> 2) & 15, w = t & 3;
      lds[t] = W[327680 + (u * 16 + v) * 16 + w0 + w];
    }
    __syncthreads();
    for (int ug = 0; ug < 4; ++ug) {
      float a[16];
#pragma unroll
      for (int u2 = 0; u2 < 16; u2++) a[u2] = A[(ug * 16 + u2) * NN + nc];
      for (int v = 0; v < 16; ++v) {
        float b[5];
#pragma unroll
        for (int j = 0; j < 5; j++) b[j] = B[(160 + v * 5 + j) * NN + nc];
        float bc[5];
#pragma unroll
        for (int k = 0; k < 5; k++) {
          float t2 = 0.f;
#pragma unroll
          for (int j = 0; j < 5; j++) t2 += b[j] * CS.c022[j * 5 + k];
          bc[k] = t2;
        }
        float g4[4];
#pragma unroll
        for (int w = 0; w < 4; w++) g4[w] = 0.f;
#pragma unroll
        for (int u2 = 0; u2 < 16; u2++) {
          const float* wl = lds + (ug * 16 + u2) * 64 + v * 4;
#pragma unroll
          for (int w = 0; w < 4; w++) g4[w] += a[u2] * wl[w];
        }
#pragma unroll
        for (int w = 0; w < 4; w++)
#pragma unroll
          for (int k = 0; k < 5; k++) y[w * 5 + k] += bc[k] * g4[w];
      }
    }

    // ---- (2,0,2): W[u16][v64][w16] @507904 (single stage)
    __syncthreads();
    for (int t = tid; t < 4096; t += 256) {
      int u = t >> 8, v = (t >> 2) & 63, w = t & 3;
      lds[t] = W[507904 + (u * 64 + v) * 16 + w0 + w];
    }
    __syncthreads();
    for (int ug = 0; ug < 2; ++ug) {
      float ac[8][5];
#pragma unroll
      for (int u2 = 0; u2 < 8; u2++) {
        float a[5];
#pragma unroll
        for (int i = 0; i < 5; i++) a[i] = A[(160 + (ug * 8 + u2) * 5 + i) * NN + nc];
#pragma unroll
        for (int k = 0; k < 5; k++) {
          float t2 = 0.f;
#pragma unroll
          for (int i = 0; i < 5; i++) t2 += a[i] * CS.c202[i * 5 + k];
          ac[u2][k] = t2;
        }
      }
      float g[8][4];
#pragma unroll
      for (int u2 = 0; u2 < 8; u2++)
#pragma unroll
        for (int w = 0; w < 4; w++) g[u2][w] = 0.f;
#pragma unroll 2
      for (int v = 0; v < 64; ++v) {
        float bv = B[v * NN + nc];
#pragma unroll
        for (int u2 = 0; u2 < 8; u2++) {
          const float* wl = lds + (ug * 8 + u2) * 256 + v * 4;
#pragma unroll
          for (int w = 0; w < 4; w++) g[u2][w] += bv * wl[w];
        }
      }
#pragma unroll
      for (int u2 = 0; u2 < 8; u2++)
#pragma unroll
        for (int w = 0; w < 4; w++)
#pragma unroll
          for (int k = 0; k < 5; k++) y[w * 5 + k] += ac[u2][k] * g[u2][w];
    }

    // ---- (1,1,2): W[u32][v32][w16] @475136 (single stage)
    __syncthreads();
    for (int t = tid; t < 4096; t += 256) {
      int u = t >> 7, v = (t >> 2) & 31, w = t & 3;
      lds[t] = W[475136 + (u * 32 + v) * 16 + w0 + w];
    }
    __syncthreads();
    for (int ug = 0; ug < 4; ++ug) {
      float a[8][3];
#pragma unroll
      for (int u2 = 0; u2 < 8; u2++)
#pragma unroll
        for (int i = 0; i < 3; i++) a[u2][i] = A[(64 + (ug * 8 + u2) * 3 + i) * NN + nc];
#pragma unroll 2
      for (int v = 0; v < 32; ++v) {
        float b0 = B[(64 + v * 3 + 0) * NN + nc], b1 = B[(64 + v * 3 + 1) * NN + nc],
              b2 = B[(64 + v * 3 + 2) * NN + nc];
        float bt[15];
#pragma unroll
        for (int i = 0; i < 3; i++)
#pragma unroll
          for (int k = 0; k < 5; k++)
            bt[i * 5 + k] = b0 * CP.c112[(i * 3 + 0) * 5 + k] + b1 * CP.c112[(i * 3 + 1) * 5 + k] +
                            b2 * CP.c112[(i * 3 + 2) * 5 + k];
#pragma unroll
        for (int u2 = 0; u2 < 8; u2++) {
          float P[5];
#pragma unroll
          for (int k = 0; k < 5; k++)
            P[k] = a[u2][0] * bt[k] + a[u2][1] * bt[5 + k] + a[u2][2] * bt[10 + k];
          const float* wl = lds + ((ug * 8 + u2) * 32 + v) * 4;
#pragma unroll
          for (int w = 0; w < 4; w++)
#pragma unroll
            for (int k = 0; k < 5; k++) y[w * 5 + k] += P[k] * wl[w];
        }
      }
    }

    // ---- (2,2,2): W[u16][v16][w16] @557056 (single stage, 1024 floats)
    __syncthreads();
    for (int t = tid; t < 1024; t += 256) {
      int u = t >> 6, v = (t >> 2) & 15, w = t & 3;
      lds[t] = W[557056 + (u * 16 + v) * 16 + w0 + w];
    }
    __syncthreads();
    for (int ug = 0; ug < 2; ++ug) {
      float a[8][5];
#pragma unroll
      for (int u2 = 0; u2 < 8; u2++)
#pragma unroll
        for (int i = 0; i < 5; i++) a[u2][i] = A[(160 + (ug * 8 + u2) * 5 + i) * NN + nc];
      for (int v = 0; v < 16; ++v) {
        float b[5];
#pragma unroll
        for (int j = 0; j < 5; j++) b[j] = B[(160 + v * 5 + j) * NN + nc];
        float bt[25];
#pragma unroll
        for (int i = 0; i < 5; i++)
#pragma unroll
          for (int k = 0; k < 5; k++) {
            float t2 = 0.f;
#pragma unroll
            for (int j = 0; j < 5; j++) t2 += b[j] * CP.c222[(i * 5 + j) * 5 + k];
            bt[i * 5 + k] = t2;
          }
#pragma unroll
        for (int u2 = 0; u2 < 8; u2++) {
          float P[5];
#pragma unroll
          for (int k = 0; k < 5; k++) {
            float t2 = 0.f;
#pragma unroll
            for (int i = 0; i < 5; i++) t2 += a[u2][i] * bt[i * 5 + k];
            P[k] = t2;
          }
          const float* wl = lds + (ug * 8 + u2) * 64 + v * 4;
#pragma unroll
          for (int w = 0; w < 4; w++)
#pragma unroll
            for (int k = 0; k < 5; k++) y[w * 5 + k] += P[k] * wl[w];
        }
      }
    }

    if (act) {
#pragma unroll
      for (int w = 0; w < 4; w++)
#pragma unroll
        for (int k = 0; k < 5; k++) UPD[(160 + (w0 + w) * 5 + k) * NN + nc] = y[w * 5 + k];
    }
  }
}

// h_new = h + upd_tp + lin_upd(h)
__global__ __launch_bounds__(256) void k_apply(
    const float* __restrict__ Hsrc, const float* __restrict__ UPD,
    const float* __restrict__ Wl, float* __restrict__ Hdst) {
  int n = blockIdx.x * 256 + threadIdx.x;
  int e = blockIdx.y;
  if (n >= NN) return;
  float lin = 0.f;
  if (e < 64) {
    for (int u = 0; u < 64; u++) lin += Hsrc[u*NN+n] * Wl[u*64+e];
    lin *= 0.125f;
  } else if (e < 160) {
    int t = e - 64, v = t/3, i = t - v*3;
    for (int u = 0; u < 32; u++) lin += Hsrc[(64+u*3+i)*NN+n] * Wl[4096 + u*32+v];
    lin *= 0.17677669529663687f;
  } else {
    int t = e - 160, v = t/5, i = t - v*5;
    for (int u = 0; u < 16; u++) lin += Hsrc[(160+u*5+i)*NN+n] * Wl[5120 + u*16+v];
    lin *= 0.25f;
  }
  Hdst[e*NN + n] = Hsrc[e*NN + n] + UPD[e*NN + n] + lin;
}

__global__ __launch_bounds__(256) void k_cnt(const int* __restrict__ batch, float* __restrict__ CNT) {
  int n = blockIdx.x * 256 + threadIdx.x;
  if (n >= NN) return;
  atomicAdd(&CNT[batch[n]], 1.0f);
}

__global__ __launch_bounds__(256) void k_pool(
    const float* __restrict__ HT, const int* __restrict__ batch, float* __restrict__ POOL) {
  int n = blockIdx.x * 256 + threadIdx.x;
  int w = blockIdx.y;
  if (n >= NN) return;
  atomicAdd(&POOL[batch[n]*64 + w], HT[w*NN + n]);
}

__global__ __launch_bounds__(256) void k_out(
    const float* __restrict__ POOL, const float* __restrict__ CNT,
    const float* __restrict__ wf, float* __restrict__ out) {
  int tid = blockIdx.x * 256 + threadIdx.x;
  if (tid >= NG * 128) return;
  int g = tid >> 7, d = tid & 127;
  float inv = 1.0f / fmaxf(CNT[g], 1.0f);
  float acc = 0.f;
  for (int w = 0; w < 64; w++) acc += POOL[g*64 + w] * wf[w*128 + d];
  out[tid] = acc * inv * 0.125f;
}

// ---------------- host-side real Wigner-3j (mirrors the reference) ----------------
typedef std::complex<double> cd;
static double hfact(int nn) { double f = 1; for (int i = 2; i <= nn; i++) f *= i; return f; }
static double hcg(int j1,int m1,int j2,int m2,int j3,int m3) {
  if (m1 + m2 != m3) return 0.0;
  double pre = sqrt((2*j3+1) * hfact(j3+j1-j2) * hfact(j3-j1+j2) * hfact(j1+j2-j3) / hfact(j1+j2+j3+1));
  pre *= sqrt(hfact(j3+m3)*hfact(j3-m3)*hfact(j1-m1)*hfact(j1+m1)*hfact(j2-m2)*hfact(j2+m2));
  double s = 0;
  for (int k = 0; k <= j1+j2-j3; k++) {
    int a1=j1+j2-j3-k, a2=j1-m1-k, a3=j2+m2-k, a4=j3-j2+m1+k, a5=j3-j1-m2+k;
    if (a1<0||a2<0||a3<0||a4<0||a5<0) continue;
    s += ((k&1)?-1.0:1.0) / (hfact(k)*hfact(a1)*hfact(a2)*hfact(a3)*hfact(a4)*hfact(a5));
  }
  return pre * s;
}
static void hA(int l, cd A[5][5]) {
  for (int r = 0; r < 5; r++) for (int c = 0; c < 5; c++) A[r][c] = cd(0,0);
  A[l][l] = cd(1,0);
  for (int m = 1; m <= l; m++) {
    double sg = (m & 1) ? -1.0 : 1.0;
    A[l+m][l+m] = cd(sg/sqrt(2.0), 0);
    A[l+m][l-m] = cd(1.0/sqrt(2.0), 0);
    A[l-m][l+m] = cd(0, -sg/sqrt(2.0));
    A[l-m][l-m] = cd(0, 1.0/sqrt(2.0));
  }
}
static void hw3j(int l1, int l2, int l3, double* out) {
  int n1 = 2*l1+1, n2 = 2*l2+1, n3 = 2*l3+1;
  double Wc[5][5][5]; memset(Wc, 0, sizeof Wc);
  for (int m1 = -l1; m1 <= l1; m1++) for (int m2 = -l2; m2 <= l2; m2++) {
    int m3 = -(m1+m2);
    if (m3 < -l3 || m3 > l3) continue;
    int ex = l1 - l2 - m3;
    double sg = (ex % 2 == 0) ? 1.0 : -1.0;
    Wc[m1+l1][m2+l2][m3+l3] = sg / sqrt((double)(2*l3+1)) * hcg(l1,m1,l2,m2,l3,-m3);
  }
  cd A1[5][5], A2[5][5], A3[5][5];
  hA(l1,A1); hA(l2,A2); hA(l3,A3);
  double nrm = 0;
  for (int a = 0; a < n1; a++) for (int b = 0; b < n2; b++) for (int c = 0; c < n3; c++) {
    cd acc(0,0);
    for (int d = 0; d < n1; d++) for (int e = 0; e < n2; e++) for (int f = 0; f < n3; f++) {
      double w = Wc[d][e][f];
      if (w == 0.0) continue;
      acc += A1[a][d] * A2[b][e] * A3[c][f] * w;
    }
    out[(a*n2+b)*n3+c] = acc.real();
    nrm += acc.real() * acc.real();
  }
  nrm = sqrt(nrm);
  for (int i = 0; i < n1*n2*n3; i++) out[i] /= nrm;
}

// ---------------- launch ----------------
extern "C" void kernel_launch(void* const* d_in, const int* in_sizes, int n_in,
                              void* d_out, int out_size, void* d_ws, size_t ws_size,
                              hipStream_t stream) {
  const float* x        = (const float*)d_in[0];
  const float* pos      = (const float*)d_in[1];
  const float* w_init   = (const float*)d_in[2];
  const float* w_tp_msg = (const float*)d_in[3];
  const float* w_lin_msg= (const float*)d_in[4];
  const float* w_tp_upd = (const float*)d_in[5];
  const float* w_lin_upd= (const float*)d_in[6];
  const float* w_final  = (const float*)d_in[7];
  const int*   ei       = (const int*)d_in[8];
  const int*   batch    = (const int*)d_in[9];
  float* out = (float*)d_out;
  float* ws  = (float*)d_ws;

  // workspace layout (floats)
  float* EA     = ws;                      // 640000
  float* CN     = EA + 640000;             // 5760000
  float* HTA    = CN + 5760000;            // 2400000
  float* HTB    = HTA + 2400000;           // 2400000
  float* Z      = HTB + 2400000;           // 9120000
  float* AGG_NM = Z + 9120000;             // 2400000
  float* UPD_T  = AGG_NM + 2400000;        // 2400000
  float* AGG_T  = UPD_T + 2400000;         // 2400000
  float* POOL   = AGG_T + 2400000;         // 4096
  float* CNT    = POOL + 4096;             // 64

  // ---- host: compute real-w3j tensors and fill coefficient structs ----
  double C000d[1], C011d[9], C101d[9], C110d[9], C112d[45], C022d[25],
         C202d[25], C121d[45], C211d[45], C220d[25], C222d[125];
  hw3j(0,0,0,C000d); hw3j(0,1,1,C011d); hw3j(1,0,1,C101d); hw3j(1,1,0,C110d);
  hw3j(1,1,2,C112d); hw3j(0,2,2,C022d); hw3j(2,0,2,C202d); hw3j(1,2,1,C121d);
  hw3j(2,1,1,C211d); hw3j(2,2,0,C220d); hw3j(2,2,2,C222d);

  CMsgPre cmsg;
  cmsg.a000 = (float)(C000d[0] / sqrt(128.0));
  cmsg.a011 = (float)(1.0 / sqrt(192.0));
  cmsg.a110 = (float)(1.0 / sqrt(64.0));
  cmsg.a112 = (float)(1.0 / sqrt(64.0));
  cmsg.a211 = (float)(1.0 / sqrt(48.0));
  for (int i = 0; i < 9;  i++) cmsg.c101[i] = (float)(C101d[i] / sqrt(96.0));
  for (int i = 0; i < 25; i++) cmsg.c202[i] = (float)(C202d[i] / sqrt(32.0));

  CEdge ce;
  for (int i = 0; i < 9;  i++) ce.c011[i] = (float)C011d[i];
  for (int i = 0; i < 9;  i++) ce.c110[i] = (float)C110d[i];
  for (int i = 0; i < 45; i++) ce.c112[i] = (float)C112d[i];
  for (int i = 0; i < 45; i++) ce.c211[i] = (float)C211d[i];

  CUpdS cus;
  cus.s000 = (float)(C000d[0] / sqrt(64.0*64.0*3.0));
  for (int i = 0; i < 9;  i++) cus.c011[i] = (float)(C011d[i] / sqrt(64.0*32.0*4.0));
  for (int i = 0; i < 25; i++) cus.c022[i] = (float)(C022d[i] / sqrt(64.0*16.0*4.0));
  for (int i = 0; i < 9;  i++) cus.c101[i] = (float)(C101d[i] / sqrt(32.0*64.0*4.0));
  for (int i = 0; i < 25; i++) cus.c202[i] = (float)(C202d[i] / sqrt(16.0*64.0*4.0));

  CUpdD cud;
  for (int i = 0; i < 9;  i++) cud.c110[i] = (float)(C110d[i] / sqrt(32.0*32.0*3.0));
  for (int i = 0; i < 25; i++) cud.c220[i] = (float)(C220d[i] / sqrt(16.0*16.0*3.0));

  CUpdP cup;
  for (int i = 0; i < 45;  i++) cup.c112[i] = (float)(C112d[i] / sqrt(32.0*32.0*4.0));
  for (int i = 0; i < 45;  i++) cup.c121[i] = (float)(C121d[i] / sqrt(32.0*16.0*4.0));
  for (int i = 0; i < 45;  i++) cup.c211[i] = (float)(C211d[i] / sqrt(16.0*32.0*4.0));
  for (int i = 0; i < 125; i++) cup.c222[i] = (float)(C222d[i] / sqrt(16.0*16.0*4.0));

  // ---- launches ----
  k_edge_attr<<<(NE+255)/256, 256, 0, stream>>>(pos, ei, ce, EA, CN);
  k_h_init<<<dim3(40, HD), 256, 0, stream>>>(x, w_init, HTA);

  float* cur = HTA;
  float* nxt = HTB;
  for (int L = 0; L < 6; L++) {
    hipMemsetAsync(AGG_NM, 0, (size_t)2400000 * sizeof(float), stream);
    k_node_pre<<<dim3(40, ZD), 256, 0, stream>>>(cur, w_tp_msg + (size_t)L*MSG_WS,
                                                 w_lin_msg + (size_t)L*LIN_WS, cmsg, Z);
    k_edge<<<1280, 256, 0, stream>>>(ei, EA, CN, Z, AGG_NM);
    k_transpose<<<dim3(40, HD), 256, 0, stream>>>(AGG_NM, AGG_T);
    const float* Wu = w_tp_upd + (size_t)L*UPD_WS;
    k_upd<<<dim3(40, 12), 256, 0, stream>>>(cur, AGG_T, Wu, cus, cud, cup, UPD_T);
    k_apply<<<dim3(40, HD), 256, 0, stream>>>(cur, UPD_T, w_lin_upd + (size_t)L*LIN_WS, nxt);
    float* tmp = cur; cur = nxt; nxt = tmp;
  }

  hipMemsetAsync(POOL, 0, (size_t)(4096 + 64) * sizeof(float), stream);
  k_cnt<<<(NN+255)/256, 256, 0, stream>>>(batch, CNT);
  k_pool<<<dim3(40, 64), 256, 0, stream>>>(cur, batch, POOL);
  k_out<<<32, 256, 0, stream>>>(POOL, CNT, w_final, out);
}

// Round 3
// 5464.172 us; speedup vs baseline: 1.4978x; 1.0104x over previous
//
#include <hip/hip_runtime.h>
#include <cmath>
#include <cstring>
#include <complex>

#define NN 10000
#define NE 160000
#define HD 240
#define ZD 912
#define NG 64
#define MSG_WS 10496
#define UPD_WS 561152
#define LIN_WS 5376

// ---------------- kernarg coefficient structs ----------------
struct CMsgPre { float a000, a011, a110, a112, a211; float c101[9]; float c202[25]; };
struct CEdge   { float c011[9]; float c110[9]; float c112[45]; float c211[45]; };
struct CUpdS   { float s000; float c011[9]; float c022[25]; float c101[9]; float c202[25]; };
struct CUpdD   { float c110[9]; float c220[25]; };
struct CUpdP   { float c112[45]; float c121[45]; float c211[45]; float c222[125]; };

// ---------------- kernels ----------------

__global__ __launch_bounds__(256) void k_edge_attr(
    const float* __restrict__ pos, const int* __restrict__ ei, CEdge C,
    float* __restrict__ EA, float* __restrict__ CN) {
  int e = blockIdx.x * 256 + threadIdx.x;
  if (e >= NE) return;
  int r = ei[e], c = ei[NE + e];
  float dx = pos[r*3+0] - pos[c*3+0];
  float dy = pos[r*3+1] - pos[c*3+1];
  float dz = pos[r*3+2] - pos[c*3+2];
  float d = sqrtf(dx*dx + dy*dy + dz*dz);
  float inv = 1.0f / fmaxf(d, 1e-8f);
  float n0 = dx*inv, n1 = dy*inv, n2 = dz*inv;
  EA[e*4+0] = d; EA[e*4+1] = n0; EA[e*4+2] = n1; EA[e*4+3] = n2;
  float* cn = CN + (size_t)e*36;
#pragma unroll
  for (int k = 0; k < 3; k++)
    cn[k] = n0*C.c011[0*3+k] + n1*C.c011[1*3+k] + n2*C.c011[2*3+k];
#pragma unroll
  for (int i = 0; i < 3; i++)
    cn[3+i] = n0*C.c110[i*3+0] + n1*C.c110[i*3+1] + n2*C.c110[i*3+2];
#pragma unroll
  for (int i = 0; i < 3; i++)
#pragma unroll
    for (int k = 0; k < 5; k++)
      cn[6+i*5+k] = n0*C.c112[(i*3+0)*5+k] + n1*C.c112[(i*3+1)*5+k] + n2*C.c112[(i*3+2)*5+k];
#pragma unroll
  for (int i = 0; i < 5; i++)
#pragma unroll
    for (int k = 0; k < 3; k++)
      cn[21+i*3+k] = n0*C.c211[(i*3+0)*3+k] + n1*C.c211[(i*3+1)*3+k] + n2*C.c211[(i*3+2)*3+k];
}

__global__ __launch_bounds__(256) void k_h_init(
    const float* __restrict__ x, const float* __restrict__ wi, float* __restrict__ HT) {
  int n = blockIdx.x * 256 + threadIdx.x;
  int e = blockIdx.y;
  if (n >= NN) return;
  float v = 0.f;
  if (e < 64)
    v = (x[n*3+0]*wi[0*64+e] + x[n*3+1]*wi[64+e] + x[n*3+2]*wi[128+e]) * 0.57735026918962576f;
  HT[e*NN + n] = v;
}

__global__ __launch_bounds__(256) void k_node_pre(
    const float* __restrict__ HT, const float* __restrict__ Wm, const float* __restrict__ Wl,
    CMsgPre C, float* __restrict__ Z) {
  int n = blockIdx.x * 256 + threadIdx.x;
  int widx = blockIdx.y;
  if (n >= NN) return;
  float acc = 0.f;
  if (widx < 64) {
    int w = widx;
    for (int u = 0; u < 64; u++) acc += HT[u*NN+n] * Wm[u*64+w];
    acc *= C.a000;
  } else if (widx < 96) {
    int w = widx - 64;
    for (int u = 0; u < 64; u++) acc += HT[u*NN+n] * Wm[4096 + u*32+w];
    acc *= C.a011;
  } else if (widx < 192) {
    int t = widx - 96, w = t/3, k = t - w*3;
    for (int u = 0; u < 32; u++) {
      float g = HT[(64+u*3+0)*NN+n]*C.c101[0*3+k]
              + HT[(64+u*3+1)*NN+n]*C.c101[1*3+k]
              + HT[(64+u*3+2)*NN+n]*C.c101[2*3+k];
      acc += Wm[6144 + u*32+w] * g;
    }
  } else if (widx < 384) {
    int t = widx - 192, w = t/3, i = t - w*3;
    for (int u = 0; u < 32; u++) acc += HT[(64+u*3+i)*NN+n] * Wm[7168 + u*64+w];
    acc *= C.a110;
  } else if (widx < 432) {
    int t = widx - 384, w = t/3, i = t - w*3;
    for (int u = 0; u < 32; u++) acc += HT[(64+u*3+i)*NN+n] * Wm[9216 + u*16+w];
    acc *= C.a112;
  } else if (widx < 512) {
    int t = widx - 432, w = t/5, k = t - w*5;
    for (int u = 0; u < 16; u++) {
      float g = 0.f;
#pragma unroll
      for (int i = 0; i < 5; i++) g += HT[(160+u*5+i)*NN+n] * C.c202[i*5+k];
      acc += Wm[9728 + u*16+w] * g;
    }
  } else if (widx < 672) {
    int t = widx - 512, w = t/5, i = t - w*5;
    for (int u = 0; u < 16; u++) acc += HT[(160+u*5+i)*NN+n] * Wm[9984 + u*32+w];
    acc *= C.a211;
  } else {
    int e2 = widx - 672;
    if (e2 < 64) {
      for (int u = 0; u < 64; u++) acc += HT[u*NN+n] * Wl[u*64+e2];
      acc *= 0.125f;
    } else if (e2 < 160) {
      int t = e2 - 64, v = t/3, i = t - v*3;
      for (int u = 0; u < 32; u++) acc += HT[(64+u*3+i)*NN+n] * Wl[4096 + u*32+v];
      acc *= 0.17677669529663687f;
    } else {
      int t = e2 - 160, v = t/5, i = t - v*5;
      for (int u = 0; u < 16; u++) acc += HT[(160+u*5+i)*NN+n] * Wl[5120 + u*16+v];
      acc *= 0.25f;
    }
  }
  Z[(size_t)n*ZD + widx] = acc;
}

__global__ __launch_bounds__(256) void k_edge(
    const int* __restrict__ ei, const float* __restrict__ EA, const float* __restrict__ CN,
    const float* __restrict__ Z, float* __restrict__ AGG) {
  __shared__ float zsh[4][ZD];
  int lane = threadIdx.x & 63, wid = threadIdx.x >> 6;
  int wg = blockIdx.x * 4 + wid;
  int stride = gridDim.x * 4;
  int iters = (NE + stride - 1) / stride;
  for (int it = 0; it < iters; ++it) {
    int e = wg + it * stride;
    bool act = e < NE;
    int r = 0;
    float s = 0.f;
    const float* cn = CN;
    if (act) {
      r = ei[e];
      int c = ei[NE + e];
      s = EA[e*4];
      cn = CN + (size_t)e*36;
      const float* zr = Z + (size_t)c*ZD;
      for (int t = lane; t < ZD; t += 64) zsh[wid][t] = zr[t];
    }
    __syncthreads();
    if (act) {
      const float* z = zsh[wid];
#pragma unroll
      for (int j = 0; j < 4; j++) {
        int idx = lane + 64*j;
        if (idx < HD) {
          float y = z[672 + idx];
          if (idx < 64) {
            int w = idx;
            y += s * z[w];
#pragma unroll
            for (int i = 0; i < 3; i++) y += z[192 + w*3 + i] * cn[3+i];
          } else if (idx < 160) {
            int t = idx - 64, w = t/3, k = t - w*3;
            y += cn[k] * z[64 + w] + s * z[96 + t];
#pragma unroll
            for (int i = 0; i < 5; i++) y += z[512 + w*5 + i] * cn[21 + i*3 + k];
          } else {
            int t = idx - 160, w = t/5, k = t - w*5;
            y += s * z[432 + t];
#pragma unroll
            for (int i = 0; i < 3; i++) y += z[384 + w*3 + i] * cn[6 + i*5 + k];
          }
          atomicAdd(&AGG[(size_t)r*HD + idx], y);
        }
      }
    }
    __syncthreads();
  }
}

__global__ __launch_bounds__(256) void k_transpose(
    const float* __restrict__ A_nm, float* __restrict__ A_t) {
  int n = blockIdx.x * 256 + threadIdx.x;
  int e = blockIdx.y;
  if (n >= NN) return;
  A_t[e*NN + n] = A_nm[(size_t)n*HD + e];
}

// ---------- unified update-TP kernel, NPT=2, float4 LDS, 28 balanced pieces ----------
// grid = (40, 28): py 0-15 -> l=0 (w-chunks of 4); 16-23 -> l=1 (w4); 24-27 -> l=2 (w4).
__global__ __launch_bounds__(128, 2) void k_upd(
    const float* __restrict__ A,   // HT  (h, elem-major)
    const float* __restrict__ B,   // AGT (agg, elem-major)
    const float* __restrict__ W,
    CUpdS CS, CUpdD CD, CUpdP CP,
    float* __restrict__ UPD) {
  __shared__ float4 lds4[1024];
  const int tid = threadIdx.x;
  const int n0 = blockIdx.x * 256 + tid;
  const int n1 = n0 + 128;
  const bool ok0 = n0 < NN, ok1 = n1 < NN;
  const int nc0 = ok0 ? n0 : NN - 1;
  const int nc1 = ok1 ? n1 : NN - 1;
  const int py = blockIdx.y;

#define LDA2(dst, e) { int _e=(e); dst.x = A[_e*NN+nc0]; dst.y = A[_e*NN+nc1]; }
#define LDB2(dst, e) { int _e=(e); dst.x = B[_e*NN+nc0]; dst.y = B[_e*NN+nc1]; }

  if (py < 16) {
    // ===== l=0 outputs, w0 = 4*py: paths (000),(110),(220) =====
    const int w04 = py;
    float2 y[4];
#pragma unroll
    for (int w = 0; w < 4; w++) y[w] = make_float2(0.f, 0.f);

    // ---- (0,0,0) @0, ws4=16, u-chunks of 16
    {
      const float4* W4 = (const float4*)W;
      for (int uc = 0; uc < 4; ++uc) {
        __syncthreads();
        for (int t = tid; t < 1024; t += 128) lds4[t] = W4[(uc*1024 + t)*16 + w04];
        __syncthreads();
        float2 ha[16];
#pragma unroll
        for (int u = 0; u < 16; ++u) {
          LDA2(ha[u], uc*16 + u);
          ha[u].x *= CS.s000; ha[u].y *= CS.s000;
        }
        for (int v = 0; v < 64; ++v) {
          float2 bv; LDB2(bv, v);
#pragma unroll
          for (int u = 0; u < 16; ++u) {
            float4 wl = lds4[u*64 + v];
            float px = ha[u].x * bv.x, qx = ha[u].y * bv.y;
            y[0].x += px*wl.x; y[0].y += qx*wl.x;
            y[1].x += px*wl.y; y[1].y += qx*wl.y;
            y[2].x += px*wl.z; y[2].y += qx*wl.z;
            y[3].x += px*wl.w; y[3].y += qx*wl.w;
          }
        }
      }
    }

    // ---- (1,1,0) @409600, ws4=16, single stage [32][32]
    {
      const float4* W4 = (const float4*)(W + 409600);
      __syncthreads();
      for (int t = tid; t < 1024; t += 128) lds4[t] = W4[t*16 + w04];
      __syncthreads();
      for (int uc = 0; uc < 4; ++uc) {
        float2 a[8][3];
#pragma unroll
        for (int u = 0; u < 8; ++u)
#pragma unroll
          for (int i = 0; i < 3; ++i) LDA2(a[u][i], 64 + (uc*8+u)*3 + i);
        for (int v = 0; v < 32; ++v) {
          float2 b[3];
#pragma unroll
          for (int j = 0; j < 3; ++j) LDB2(b[j], 64 + v*3 + j);
          float2 bt[3];
#pragma unroll
          for (int i = 0; i < 3; ++i) {
            bt[i].x = CD.c110[i*3+0]*b[0].x + CD.c110[i*3+1]*b[1].x + CD.c110[i*3+2]*b[2].x;
            bt[i].y = CD.c110[i*3+0]*b[0].y + CD.c110[i*3+1]*b[1].y + CD.c110[i*3+2]*b[2].y;
          }
#pragma unroll
          for (int u = 0; u < 8; ++u) {
            float Dx = a[u][0].x*bt[0].x + a[u][1].x*bt[1].x + a[u][2].x*bt[2].x;
            float Dy = a[u][0].y*bt[0].y + a[u][1].y*bt[1].y + a[u][2].y*bt[2].y;
            float4 wl = lds4[(uc*8+u)*32 + v];
            y[0].x += Dx*wl.x; y[0].y += Dy*wl.x;
            y[1].x += Dx*wl.y; y[1].y += Dy*wl.y;
            y[2].x += Dx*wl.z; y[2].y += Dy*wl.z;
            y[3].x += Dx*wl.w; y[3].y += Dy*wl.w;
          }
        }
      }
    }

    // ---- (2,2,0) @540672, ws4=16, single stage [16][16]
    {
      const float4* W4 = (const float4*)(W + 540672);
      __syncthreads();
      for (int t = tid; t < 256; t += 128) lds4[t] = W4[t*16 + w04];
      __syncthreads();
      for (int uc = 0; uc < 4; ++uc) {
        float2 a[4][5];
#pragma unroll
        for (int u = 0; u < 4; ++u)
#pragma unroll
          for (int i = 0; i < 5; ++i) LDA2(a[u][i], 160 + (uc*4+u)*5 + i);
        for (int v = 0; v < 16; ++v) {
          float2 b[5];
#pragma unroll
          for (int j = 0; j < 5; ++j) LDB2(b[j], 160 + v*5 + j);
          float2 bt[5];
#pragma unroll
          for (int i = 0; i < 5; ++i) {
            float tx = 0.f, ty = 0.f;
#pragma unroll
            for (int j = 0; j < 5; ++j) { tx += CD.c220[i*5+j]*b[j].x; ty += CD.c220[i*5+j]*b[j].y; }
            bt[i].x = tx; bt[i].y = ty;
          }
#pragma unroll
          for (int u = 0; u < 4; ++u) {
            float Dx = 0.f, Dy = 0.f;
#pragma unroll
            for (int i = 0; i < 5; ++i) { Dx += a[u][i].x*bt[i].x; Dy += a[u][i].y*bt[i].y; }
            float4 wl = lds4[(uc*4+u)*16 + v];
            y[0].x += Dx*wl.x; y[0].y += Dy*wl.x;
            y[1].x += Dx*wl.y; y[1].y += Dy*wl.y;
            y[2].x += Dx*wl.z; y[2].y += Dy*wl.z;
            y[3].x += Dx*wl.w; y[3].y += Dy*wl.w;
          }
        }
      }
    }

#pragma unroll
    for (int w = 0; w < 4; ++w) {
      if (ok0) UPD[(py*4 + w)*NN + n0] = y[w].x;
      if (ok1) UPD[(py*4 + w)*NN + n1] = y[w].y;
    }

  } else if (py < 24) {
    // ===== l=1 outputs, w0 = 4*(py-16): paths (011),(101),(121),(211) =====
    const int w04 = py - 16;
    float2 y[4][3];
#pragma unroll
    for (int w = 0; w < 4; w++)
#pragma unroll
      for (int k = 0; k < 3; k++) y[w][k] = make_float2(0.f, 0.f);

    // ---- (0,1,1) @262144, ws4=8, u-chunks of 32
    {
      const float4* W4 = (const float4*)(W + 262144);
      for (int uc = 0; uc < 2; ++uc) {
        __syncthreads();
        for (int t = tid; t < 1024; t += 128) lds4[t] = W4[(uc*1024 + t)*8 + w04];
        __syncthreads();
        float2 a[32];
#pragma unroll
        for (int u = 0; u < 32; ++u) LDA2(a[u], uc*32 + u);
        for (int v = 0; v < 32; ++v) {
          float2 b[3];
#pragma unroll
          for (int j = 0; j < 3; ++j) LDB2(b[j], 64 + v*3 + j);
          float2 bc[3];
#pragma unroll
          for (int k = 0; k < 3; ++k) {
            bc[k].x = b[0].x*CS.c011[k] + b[1].x*CS.c011[3+k] + b[2].x*CS.c011[6+k];
            bc[k].y = b[0].y*CS.c011[k] + b[1].y*CS.c011[3+k] + b[2].y*CS.c011[6+k];
          }
          float2 g[4];
#pragma unroll
          for (int w = 0; w < 4; w++) g[w] = make_float2(0.f, 0.f);
#pragma unroll
          for (int u = 0; u < 32; ++u) {
            float4 wl = lds4[u*32 + v];
            g[0].x += a[u].x*wl.x; g[0].y += a[u].y*wl.x;
            g[1].x += a[u].x*wl.y; g[1].y += a[u].y*wl.y;
            g[2].x += a[u].x*wl.z; g[2].y += a[u].y*wl.z;
            g[3].x += a[u].x*wl.w; g[3].y += a[u].y*wl.w;
          }
#pragma unroll
          for (int w = 0; w < 4; ++w)
#pragma unroll
            for (int k = 0; k < 3; ++k) {
              y[w][k].x += bc[k].x*g[w].x; y[w][k].y += bc[k].y*g[w].y;
            }
        }
      }
    }

    // ---- (1,0,1) @344064, ws4=8, u-chunks of 16, v-chunks of 16
    {
      const float4* W4 = (const float4*)(W + 344064);
      for (int uc = 0; uc < 2; ++uc) {
        __syncthreads();
        for (int t = tid; t < 1024; t += 128) lds4[t] = W4[(uc*1024 + t)*8 + w04];
        __syncthreads();
        for (int vc = 0; vc < 4; ++vc) {
          float2 bv[16];
#pragma unroll
          for (int v2 = 0; v2 < 16; ++v2) LDB2(bv[v2], vc*16 + v2);
          for (int u = 0; u < 16; ++u) {
            float2 aa[3];
#pragma unroll
            for (int i = 0; i < 3; ++i) LDA2(aa[i], 64 + (uc*16+u)*3 + i);
            float2 ac[3];
#pragma unroll
            for (int k = 0; k < 3; ++k) {
              ac[k].x = aa[0].x*CS.c101[k] + aa[1].x*CS.c101[3+k] + aa[2].x*CS.c101[6+k];
              ac[k].y = aa[0].y*CS.c101[k] + aa[1].y*CS.c101[3+k] + aa[2].y*CS.c101[6+k];
            }
            float2 gp[4];
#pragma unroll
            for (int w = 0; w < 4; w++) gp[w] = make_float2(0.f, 0.f);
#pragma unroll
            for (int v2 = 0; v2 < 16; ++v2) {
              float4 wl = lds4[u*64 + vc*16 + v2];
              gp[0].x += bv[v2].x*wl.x; gp[0].y += bv[v2].y*wl.x;
              gp[1].x += bv[v2].x*wl.y; gp[1].y += bv[v2].y*wl.y;
              gp[2].x += bv[v2].x*wl.z; gp[2].y += bv[v2].y*wl.z;
              gp[3].x += bv[v2].x*wl.w; gp[3].y += bv[v2].y*wl.w;
            }
#pragma unroll
            for (int w = 0; w < 4; ++w)
#pragma unroll
              for (int k = 0; k < 3; ++k) {
                y[w][k].x += ac[k].x*gp[w].x; y[w][k].y += ac[k].y*gp[w].y;
              }
          }
        }
      }
    }

    // ---- (1,2,1) @491520, ws4=8, single stage [32][16]
    {
      const float4* W4 = (const float4*)(W + 491520);
      __syncthreads();
      for (int t = tid; t < 512; t += 128) lds4[t] = W4[t*8 + w04];
      __syncthreads();
      for (int uc = 0; uc < 4; ++uc) {
        float2 a[8][3];
#pragma unroll
        for (int u = 0; u < 8; ++u)
#pragma unroll
          for (int i = 0; i < 3; ++i) LDA2(a[u][i], 64 + (uc*8+u)*3 + i);
        for (int v = 0; v < 16; ++v) {
          float2 b[5];
#pragma unroll
          for (int j = 0; j < 5; ++j) LDB2(b[j], 160 + v*5 + j);
          float2 bt[3][3];
#pragma unroll
          for (int i = 0; i < 3; ++i)
#pragma unroll
            for (int k = 0; k < 3; ++k) {
              float tx = 0.f, ty = 0.f;
#pragma unroll
              for (int j = 0; j < 5; ++j) { tx += b[j].x*CP.c121[(i*5+j)*3+k]; ty += b[j].y*CP.c121[(i*5+j)*3+k]; }
              bt[i][k].x = tx; bt[i][k].y = ty;
            }
#pragma unroll
          for (int u = 0; u < 8; ++u) {
            float2 P[3];
#pragma unroll
            for (int k = 0; k < 3; ++k) {
              P[k].x = a[u][0].x*bt[0][k].x + a[u][1].x*bt[1][k].x + a[u][2].x*bt[2][k].x;
              P[k].y = a[u][0].y*bt[0][k].y + a[u][1].y*bt[1][k].y + a[u][2].y*bt[2][k].y;
            }
            float4 wl = lds4[(uc*8+u)*16 + v];
#pragma unroll
            for (int k = 0; k < 3; ++k) {
              y[0][k].x += P[k].x*wl.x; y[0][k].y += P[k].y*wl.x;
              y[1][k].x += P[k].x*wl.y; y[1][k].y += P[k].y*wl.y;
              y[2][k].x += P[k].x*wl.z; y[2][k].y += P[k].y*wl.z;
              y[3][k].x += P[k].x*wl.w; y[3][k].y += P[k].y*wl.w;
            }
          }
        }
      }
    }

    // ---- (2,1,1) @524288, ws4=8, single stage [16][32]
    {
      const float4* W4 = (const float4*)(W + 524288);
      __syncthreads();
      for (int t = tid; t < 512; t += 128) lds4[t] = W4[t*8 + w04];
      __syncthreads();
      for (int uc = 0; uc < 2; ++uc) {
        float2 a[8][5];
#pragma unroll
        for (int u = 0; u < 8; ++u)
#pragma unroll
          for (int i = 0; i < 5; ++i) LDA2(a[u][i], 160 + (uc*8+u)*5 + i);
        for (int v = 0; v < 32; ++v) {
          float2 b[3];
#pragma unroll
          for (int j = 0; j < 3; ++j) LDB2(b[j], 64 + v*3 + j);
          float2 bt[5][3];
#pragma unroll
          for (int i = 0; i < 5; ++i)
#pragma unroll
            for (int k = 0; k < 3; ++k) {
              bt[i][k].x = b[0].x*CP.c211[(i*3+0)*3+k] + b[1].x*CP.c211[(i*3+1)*3+k] + b[2].x*CP.c211[(i*3+2)*3+k];
              bt[i][k].y = b[0].y*CP.c211[(i*3+0)*3+k] + b[1].y*CP.c211[(i*3+1)*3+k] + b[2].y*CP.c211[(i*3+2)*3+k];
            }
#pragma unroll
          for (int u = 0; u < 8; ++u) {
            float2 P[3];
#pragma unroll
            for (int k = 0; k < 3; ++k) {
              float tx = 0.f, ty = 0.f;
#pragma unroll
              for (int i = 0; i < 5; ++i) { tx += a[u][i].x*bt[i][k].x; ty += a[u][i].y*bt[i][k].y; }
              P[k].x = tx; P[k].y = ty;
            }
            float4 wl = lds4[(uc*8+u)*32 + v];
#pragma unroll
            for (int k = 0; k < 3; ++k) {
              y[0][k].x += P[k].x*wl.x; y[0][k].y += P[k].y*wl.x;
              y[1][k].x += P[k].x*wl.y; y[1][k].y += P[k].y*wl.y;
              y[2][k].x += P[k].x*wl.z; y[2][k].y += P[k].y*wl.z;
              y[3][k].x += P[k].x*wl.w; y[3][k].y += P[k].y*wl.w;
            }
          }
        }
      }
    }

#pragma unroll
    for (int w = 0; w < 4; ++w)
#pragma unroll
      for (int k = 0; k < 3; ++k) {
        int e = 64 + (w04*4 + w)*3 + k;
        if (ok0) UPD[e*NN + n0] = y[w][k].x;
        if (ok1) UPD[e*NN + n1] = y[w][k].y;
      }

  } else {
    // ===== l=2 outputs, w0 = 4*(py-24): paths (022),(202),(112),(222) =====
    const int w04 = py - 24;
    float2 y[4][5];
#pragma unroll
    for (int w = 0; w < 4; w++)
#pragma unroll
      for (int k = 0; k < 5; k++) y[w][k] = make_float2(0.f, 0.f);

    // ---- (0,2,2) @327680, ws4=4, single stage [64][16]
    {
      const float4* W4 = (const float4*)(W + 327680);
      __syncthreads();
      for (int t = tid; t < 1024; t += 128) lds4[t] = W4[t*4 + w04];
      __syncthreads();
      for (int uc = 0; uc < 4; ++uc) {
        float2 a[16];
#pragma unroll
        for (int u = 0; u < 16; ++u) LDA2(a[u], uc*16 + u);
        for (int v = 0; v < 16; ++v) {
          float2 b[5];
#pragma unroll
          for (int j = 0; j < 5; ++j) LDB2(b[j], 160 + v*5 + j);
          float2 bc[5];
#pragma unroll
          for (int k = 0; k < 5; ++k) {
            float tx = 0.f, ty = 0.f;
#pragma unroll
            for (int j = 0; j < 5; ++j) { tx += b[j].x*CS.c022[j*5+k]; ty += b[j].y*CS.c022[j*5+k]; }
            bc[k].x = tx; bc[k].y = ty;
          }
          float2 g[4];
#pragma unroll
          for (int w = 0; w < 4; w++) g[w] = make_float2(0.f, 0.f);
#pragma unroll
          for (int u = 0; u < 16; ++u) {
            float4 wl = lds4[(uc*16+u)*16 + v];
            g[0].x += a[u].x*wl.x; g[0].y += a[u].y*wl.x;
            g[1].x += a[u].x*wl.y; g[1].y += a[u].y*wl.y;
            g[2].x += a[u].x*wl.z; g[2].y += a[u].y*wl.z;
            g[3].x += a[u].x*wl.w; g[3].y += a[u].y*wl.w;
          }
#pragma unroll
          for (int w = 0; w < 4; ++w)
#pragma unroll
            for (int k = 0; k < 5; ++k) {
              y[w][k].x += bc[k].x*g[w].x; y[w][k].y += bc[k].y*g[w].y;
            }
        }
      }
    }

    // ---- (2,0,2) @507904, ws4=4, single stage [16][64]
    {
      const float4* W4 = (const float4*)(W + 507904);
      __syncthreads();
      for (int t = tid; t < 1024; t += 128) lds4[t] = W4[t*4 + w04];
      __syncthreads();
      for (int vc = 0; vc < 4; ++vc) {
        float2 bv[16];
#pragma unroll
        for (int v2 = 0; v2 < 16; ++v2) LDB2(bv[v2], vc*16 + v2);
        for (int u = 0; u < 16; ++u) {
          float2 aa[5];
#pragma unroll
          for (int i = 0; i < 5; ++i) LDA2(aa[i], 160 + u*5 + i);
          float2 ac[5];
#pragma unroll
          for (int k = 0; k < 5; ++k) {
            float tx = 0.f, ty = 0.f;
#pragma unroll
            for (int i = 0; i < 5; ++i) { tx += aa[i].x*CS.c202[i*5+k]; ty += aa[i].y*CS.c202[i*5+k]; }
            ac[k].x = tx; ac[k].y = ty;
          }
          float2 gp[4];
#pragma unroll
          for (int w = 0; w < 4; w++) gp[w] = make_float2(0.f, 0.f);
#pragma unroll
          for (int v2 = 0; v2 < 16; ++v2) {
            float4 wl = lds4[u*64 + vc*16 + v2];
            gp[0].x += bv[v2].x*wl.x; gp[0].y += bv[v2].y*wl.x;
            gp[1].x += bv[v2].x*wl.y; gp[1].y += bv[v2].y*wl.y;
            gp[2].x += bv[v2].x*wl.z; gp[2].y += bv[v2].y*wl.z;
            gp[3].x += bv[v2].x*wl.w; gp[3].y += bv[v2].y*wl.w;
          }
#pragma unroll
          for (int w = 0; w < 4; ++w)
#pragma unroll
            for (int k = 0; k < 5; ++k) {
              y[w][k].x += ac[k].x*gp[w].x; y[w][k].y += ac[k].y*gp[w].y;
            }
        }
      }
    }

    // ---- (1,1,2) @475136, ws4=4, single stage [32][32]
    {
      const float4* W4 = (const float4*)(W + 475136);
      __syncthreads();
      for (int t = tid; t < 1024; t += 128) lds4[t] = W4[t*4 + w04];
      __syncthreads();
      for (int uc = 0; uc < 4; ++uc) {
        float2 a[8][3];
#pragma unroll
        for (int u = 0; u < 8; ++u)
#pragma unroll
          for (int i = 0; i < 3; ++i) LDA2(a[u][i], 64 + (uc*8+u)*3 + i);
        for (int v = 0; v < 32; ++v) {
          float2 b[3];
#pragma unroll
          for (int j = 0; j < 3; ++j) LDB2(b[j], 64 + v*3 + j);
          float2 bt[3][5];
#pragma unroll
          for (int i = 0; i < 3; ++i)
#pragma unroll
            for (int k = 0; k < 5; ++k) {
              bt[i][k].x = b[0].x*CP.c112[(i*3+0)*5+k] + b[1].x*CP.c112[(i*3+1)*5+k] + b[2].x*CP.c112[(i*3+2)*5+k];
              bt[i][k].y = b[0].y*CP.c112[(i*3+0)*5+k] + b[1].y*CP.c112[(i*3+1)*5+k] + b[2].y*CP.c112[(i*3+2)*5+k];
            }
#pragma unroll
          for (int u = 0; u < 8; ++u) {
            float2 P[5];
#pragma unroll
            for (int k = 0; k < 5; ++k) {
              P[k].x = a[u][0].x*bt[0][k].x + a[u][1].x*bt[1][k].x + a[u][2].x*bt[2][k].x;
              P[k].y = a[u][0].y*bt[0][k].y + a[u][1].y*bt[1][k].y + a[u][2].y*bt[2][k].y;
            }
            float4 wl = lds4[(uc*8+u)*32 + v];
#pragma unroll
            for (int k = 0; k < 5; ++k) {
              y[0][k].x += P[k].x*wl.x; y[0][k].y += P[k].y*wl.x;
              y[1][k].x += P[k].x*wl.y; y[1][k].y += P[k].y*wl.y;
              y[2][k].x += P[k].x*wl.z; y[2][k].y += P[k].y*wl.z;
              y[3][k].x += P[k].x*wl.w; y[3][k].y += P[k].y*wl.w;
            }
          }
        }
      }
    }

    // ---- (2,2,2) @557056, ws4=4, single stage [16][16], v-outer transient-a
    {
      const float4* W4 = (const float4*)(W + 557056);
      __syncthreads();
      for (int t = tid; t < 256; t += 128) lds4[t] = W4[t*4 + w04];
      __syncthreads();
      for (int v = 0; v < 16; ++v) {
        float2 b[5];
#pragma unroll
        for (int j = 0; j < 5; ++j) LDB2(b[j], 160 + v*5 + j);
        float2 bt[5][5];
#pragma unroll
        for (int i = 0; i < 5; ++i)
#pragma unroll
          for (int k = 0; k < 5; ++k) {
            float tx = 0.f, ty = 0.f;
#pragma unroll
            for (int j = 0; j < 5; ++j) { tx += b[j].x*CP.c222[(i*5+j)*5+k]; ty += b[j].y*CP.c222[(i*5+j)*5+k]; }
            bt[i][k].x = tx; bt[i][k].y = ty;
          }
        for (int u = 0; u < 16; ++u) {
          float2 aa[5];
#pragma unroll
          for (int i = 0; i < 5; ++i) LDA2(aa[i], 160 + u*5 + i);
          float2 P[5];
#pragma unroll
          for (int k = 0; k < 5; ++k) {
            float tx = 0.f, ty = 0.f;
#pragma unroll
            for (int i = 0; i < 5; ++i) { tx += aa[i].x*bt[i][k].x; ty += aa[i].y*bt[i][k].y; }
            P[k].x = tx; P[k].y = ty;
          }
          float4 wl = lds4[u*16 + v];
#pragma unroll
          for (int k = 0; k < 5; ++k) {
            y[0][k].x += P[k].x*wl.x; y[0][k].y += P[k].y*wl.x;
            y[1][k].x += P[k].x*wl.y; y[1][k].y += P[k].y*wl.y;
            y[2][k].x += P[k].x*wl.z; y[2][k].y += P[k].y*wl.z;
            y[3][k].x += P[k].x*wl.w; y[3][k].y += P[k].y*wl.w;
          }
        }
      }
    }

#pragma unroll
    for (int w = 0; w < 4; ++w)
#pragma unroll
      for (int k = 0; k < 5; ++k) {
        int e = 160 + (w04*4 + w)*5 + k;
        if (ok0) UPD[e*NN + n0] = y[w][k].x;
        if (ok1) UPD[e*NN + n1] = y[w][k].y;
      }
  }
#undef LDA2
#undef LDB2
}

// h_new = h + upd_tp + lin_upd(h)
__global__ __launch_bounds__(256) void k_apply(
    const float* __restrict__ Hsrc, const float* __restrict__ UPD,
    const float* __restrict__ Wl, float* __restrict__ Hdst) {
  int n = blockIdx.x * 256 + threadIdx.x;
  int e = blockIdx.y;
  if (n >= NN) return;
  float lin = 0.f;
  if (e < 64) {
    for (int u = 0; u < 64; u++) lin += Hsrc[u*NN+n] * Wl[u*64+e];
    lin *= 0.125f;
  } else if (e < 160) {
    int t = e - 64, v = t/3, i = t - v*3;
    for (int u = 0; u < 32; u++) lin += Hsrc[(64+u*3+i)*NN+n] * Wl[4096 + u*32+v];
    lin *= 0.17677669529663687f;
  } else {
    int t = e - 160, v = t/5, i = t - v*5;
    for (int u = 0; u < 16; u++) lin += Hsrc[(160+u*5+i)*NN+n] * Wl[5120 + u*16+v];
    lin *= 0.25f;
  }
  Hdst[e*NN + n] = Hsrc[e*NN + n] + UPD[e*NN + n] + lin;
}

__global__ __launch_bounds__(256) void k_cnt(const int* __restrict__ batch, float* __restrict__ CNT) {
  int n = blockIdx.x * 256 + threadIdx.x;
  if (n >= NN) return;
  atomicAdd(&CNT[batch[n]], 1.0f);
}

__global__ __launch_bounds__(256) void k_pool(
    const float* __restrict__ HT, const int* __restrict__ batch, float* __restrict__ POOL) {
  int n = blockIdx.x * 256 + threadIdx.x;
  int w = blockIdx.y;
  if (n >= NN) return;
  atomicAdd(&POOL[batch[n]*64 + w], HT[w*NN + n]);
}

__global__ __launch_bounds__(256) void k_out(
    const float* __restrict__ POOL, const float* __restrict__ CNT,
    const float* __restrict__ wf, float* __restrict__ out) {
  int tid = blockIdx.x * 256 + threadIdx.x;
  if (tid >= NG * 128) return;
  int g = tid >> 7, d = tid & 127;
  float inv = 1.0f / fmaxf(CNT[g], 1.0f);
  float acc = 0.f;
  for (int w = 0; w < 64; w++) acc += POOL[g*64 + w] * wf[w*128 + d];
  out[tid] = acc * inv * 0.125f;
}

// ---------------- host-side real Wigner-3j (mirrors the reference) ----------------
typedef std::complex<double> cd;
static double hfact(int nn) { double f = 1; for (int i = 2; i <= nn; i++) f *= i; return f; }
static double hcg(int j1,int m1,int j2,int m2,int j3,int m3) {
  if (m1 + m2 != m3) return 0.0;
  double pre = sqrt((2*j3+1) * hfact(j3+j1-j2) * hfact(j3-j1+j2) * hfact(j1+j2-j3) / hfact(j1+j2+j3+1));
  pre *= sqrt(hfact(j3+m3)*hfact(j3-m3)*hfact(j1-m1)*hfact(j1+m1)*hfact(j2-m2)*hfact(j2+m2));
  double s = 0;
  for (int k = 0; k <= j1+j2-j3; k++) {
    int a1=j1+j2-j3-k, a2=j1-m1-k, a3=j2+m2-k, a4=j3-j2+m1+k, a5=j3-j1-m2+k;
    if (a1<0||a2<0||a3<0||a4<0||a5<0) continue;
    s += ((k&1)?-1.0:1.0) / (hfact(k)*hfact(a1)*hfact(a2)*hfact(a3)*hfact(a4)*hfact(a5));
  }
  return pre * s;
}
static void hA(int l, cd A[5][5]) {
  for (int r = 0; r < 5; r++) for (int c = 0; c < 5; c++) A[r][c] = cd(0,0);
  A[l][l] = cd(1,0);
  for (int m = 1; m <= l; m++) {
    double sg = (m & 1) ? -1.0 : 1.0;
    A[l+m][l+m] = cd(sg/sqrt(2.0), 0);
    A[l+m][l-m] = cd(1.0/sqrt(2.0), 0);
    A[l-m][l+m] = cd(0, -sg/sqrt(2.0));
    A[l-m][l-m] = cd(0, 1.0/sqrt(2.0));
  }
}
static void hw3j(int l1, int l2, int l3, double* out) {
  int n1 = 2*l1+1, n2 = 2*l2+1, n3 = 2*l3+1;
  double Wc[5][5][5]; memset(Wc, 0, sizeof Wc);
  for (int m1 = -l1; m1 <= l1; m1++) for (int m2 = -l2; m2 <= l2; m2++) {
    int m3 = -(m1+m2);
    if (m3 < -l3 || m3 > l3) continue;
    int ex = l1 - l2 - m3;
    double sg = (ex % 2 == 0) ? 1.0 : -1.0;
    Wc[m1+l1][m2+l2][m3+l3] = sg / sqrt((double)(2*l3+1)) * hcg(l1,m1,l2,m2,l3,-m3);
  }
  cd A1[5][5], A2[5][5], A3[5][5];
  hA(l1,A1); hA(l2,A2); hA(l3,A3);
  double nrm = 0;
  for (int a = 0; a < n1; a++) for (int b = 0; b < n2; b++) for (int c = 0; c < n3; c++) {
    cd acc(0,0);
    for (int d = 0; d < n1; d++) for (int e = 0; e < n2; e++) for (int f = 0; f < n3; f++) {
      double w = Wc[d][e][f];
      if (w == 0.0) continue;
      acc += A1[a][d] * A2[b][e] * A3[c][f] * w;
    }
    out[(a*n2+b)*n3+c] = acc.real();
    nrm += acc.real() * acc.real();
  }
  nrm = sqrt(nrm);
  for (int i = 0; i < n1*n2*n3; i++) out[i] /= nrm;
}

// ---------------- launch ----------------
extern "C" void kernel_launch(void* const* d_in, const int* in_sizes, int n_in,
                              void* d_out, int out_size, void* d_ws, size_t ws_size,
                              hipStream_t stream) {
  const float* x        = (const float*)d_in[0];
  const float* pos      = (const float*)d_in[1];
  const float* w_init   = (const float*)d_in[2];
  const float* w_tp_msg = (const float*)d_in[3];
  const float* w_lin_msg= (const float*)d_in[4];
  const float* w_tp_upd = (const float*)d_in[5];
  const float* w_lin_upd= (const float*)d_in[6];
  const float* w_final  = (const float*)d_in[7];
  const int*   ei       = (const int*)d_in[8];
  const int*   batch    = (const int*)d_in[9];
  float* out = (float*)d_out;
  float* ws  = (float*)d_ws;

  // workspace layout (floats)
  float* EA     = ws;                      // 640000
  float* CN     = EA + 640000;             // 5760000
  float* HTA    = CN + 5760000;            // 2400000
  float* HTB    = HTA + 2400000;           // 2400000
  float* Z      = HTB + 2400000;           // 9120000
  float* AGG_NM = Z + 9120000;             // 2400000
  float* UPD_T  = AGG_NM + 2400000;        // 2400000
  float* AGG_T  = UPD_T + 2400000;         // 2400000
  float* POOL   = AGG_T + 2400000;         // 4096
  float* CNT    = POOL + 4096;             // 64

  // ---- host: compute real-w3j tensors and fill coefficient structs ----
  double C000d[1], C011d[9], C101d[9], C110d[9], C112d[45], C022d[25],
         C202d[25], C121d[45], C211d[45], C220d[25], C222d[125];
  hw3j(0,0,0,C000d); hw3j(0,1,1,C011d); hw3j(1,0,1,C101d); hw3j(1,1,0,C110d);
  hw3j(1,1,2,C112d); hw3j(0,2,2,C022d); hw3j(2,0,2,C202d); hw3j(1,2,1,C121d);
  hw3j(2,1,1,C211d); hw3j(2,2,0,C220d); hw3j(2,2,2,C222d);

  CMsgPre cmsg;
  cmsg.a000 = (float)(C000d[0] / sqrt(128.0));
  cmsg.a011 = (float)(1.0 / sqrt(192.0));
  cmsg.a110 = (float)(1.0 / sqrt(64.0));
  cmsg.a112 = (float)(1.0 / sqrt(64.0));
  cmsg.a211 = (float)(1.0 / sqrt(48.0));
  for (int i = 0; i < 9;  i++) cmsg.c101[i] = (float)(C101d[i] / sqrt(96.0));
  for (int i = 0; i < 25; i++) cmsg.c202[i] = (float)(C202d[i] / sqrt(32.0));

  CEdge ce;
  for (int i = 0; i < 9;  i++) ce.c011[i] = (float)C011d[i];
  for (int i = 0; i < 9;  i++) ce.c110[i] = (float)C110d[i];
  for (int i = 0; i < 45; i++) ce.c112[i] = (float)C112d[i];
  for (int i = 0; i < 45; i++) ce.c211[i] = (float)C211d[i];

  CUpdS cus;
  cus.s000 = (float)(C000d[0] / sqrt(64.0*64.0*3.0));
  for (int i = 0; i < 9;  i++) cus.c011[i] = (float)(C011d[i] / sqrt(64.0*32.0*4.0));
  for (int i = 0; i < 25; i++) cus.c022[i] = (float)(C022d[i] / sqrt(64.0*16.0*4.0));
  for (int i = 0; i < 9;  i++) cus.c101[i] = (float)(C101d[i] / sqrt(32.0*64.0*4.0));
  for (int i = 0; i < 25; i++) cus.c202[i] = (float)(C202d[i] / sqrt(16.0*64.0*4.0));

  CUpdD cud;
  for (int i = 0; i < 9;  i++) cud.c110[i] = (float)(C110d[i] / sqrt(32.0*32.0*3.0));
  for (int i = 0; i < 25; i++) cud.c220[i] = (float)(C220d[i] / sqrt(16.0*16.0*3.0));

  CUpdP cup;
  for (int i = 0; i < 45;  i++) cup.c112[i] = (float)(C112d[i] / sqrt(32.0*32.0*4.0));
  for (int i = 0; i < 45;  i++) cup.c121[i] = (float)(C121d[i] / sqrt(32.0*16.0*4.0));
  for (int i = 0; i < 45;  i++) cup.c211[i] = (float)(C211d[i] / sqrt(16.0*32.0*4.0));
  for (int i = 0; i < 125; i++) cup.c222[i] = (float)(C222d[i] / sqrt(16.0*16.0*4.0));

  // ---- launches ----
  k_edge_attr<<<(NE+255)/256, 256, 0, stream>>>(pos, ei, ce, EA, CN);
  k_h_init<<<dim3(40, HD), 256, 0, stream>>>(x, w_init, HTA);

  float* cur = HTA;
  float* nxt = HTB;
  for (int L = 0; L < 6; L++) {
    hipMemsetAsync(AGG_NM, 0, (size_t)2400000 * sizeof(float), stream);
    k_node_pre<<<dim3(40, ZD), 256, 0, stream>>>(cur, w_tp_msg + (size_t)L*MSG_WS,
                                                 w_lin_msg + (size_t)L*LIN_WS, cmsg, Z);
    k_edge<<<1280, 256, 0, stream>>>(ei, EA, CN, Z, AGG_NM);
    k_transpose<<<dim3(40, HD), 256, 0, stream>>>(AGG_NM, AGG_T);
    const float* Wu = w_tp_upd + (size_t)L*UPD_WS;
    k_upd<<<dim3(40, 28), 128, 0, stream>>>(cur, AGG_T, Wu, cus, cud, cup, UPD_T);
    k_apply<<<dim3(40, HD), 256, 0, stream>>>(cur, UPD_T, w_lin_upd + (size_t)L*LIN_WS, nxt);
    float* tmp = cur; cur = nxt; nxt = tmp;
  }

  hipMemsetAsync(POOL, 0, (size_t)(4096 + 64) * sizeof(float), stream);
  k_cnt<<<(NN+255)/256, 256, 0, stream>>>(batch, CNT);
  k_pool<<<dim3(40, 64), 256, 0, stream>>>(cur, batch, POOL);
  k_out<<<32, 256, 0, stream>>>(POOL, CNT, w_final, out);
}

// Round 4
// 4926.590 us; speedup vs baseline: 1.6613x; 1.1091x over previous
//
#include <hip/hip_runtime.h>
#include <cmath>
#include <cstring>
#include <complex>

#define NN 10000
#define NE 160000
#define HD 240
#define ZD 912
#define NG 64
#define MSG_WS 10496
#define UPD_WS 561152
#define LIN_WS 5376

// ---------------- kernarg coefficient structs ----------------
struct CMsgPre { float a000, a011, a110, a112, a211; float c101[9]; float c202[25]; };
struct CEdge   { float c011[9]; float c110[9]; float c112[45]; float c211[45]; };
struct CUpdS   { float s000; float c011[9]; float c022[25]; float c101[9]; float c202[25]; };
struct CUpdD   { float c110[9]; float c220[25]; };
struct CUpdP   { float c112[45]; float c121[45]; float c211[45]; float c222[125]; };

// ---------------- kernels ----------------

__global__ __launch_bounds__(256) void k_edge_attr(
    const float* __restrict__ pos, const int* __restrict__ ei, CEdge C,
    float* __restrict__ EA, float* __restrict__ CN) {
  int e = blockIdx.x * 256 + threadIdx.x;
  if (e >= NE) return;
  int r = ei[e], c = ei[NE + e];
  float dx = pos[r*3+0] - pos[c*3+0];
  float dy = pos[r*3+1] - pos[c*3+1];
  float dz = pos[r*3+2] - pos[c*3+2];
  float d = sqrtf(dx*dx + dy*dy + dz*dz);
  float inv = 1.0f / fmaxf(d, 1e-8f);
  float n0 = dx*inv, n1 = dy*inv, n2 = dz*inv;
  EA[e*4+0] = d; EA[e*4+1] = n0; EA[e*4+2] = n1; EA[e*4+3] = n2;
  float* cn = CN + (size_t)e*36;
#pragma unroll
  for (int k = 0; k < 3; k++)
    cn[k] = n0*C.c011[0*3+k] + n1*C.c011[1*3+k] + n2*C.c011[2*3+k];
#pragma unroll
  for (int i = 0; i < 3; i++)
    cn[3+i] = n0*C.c110[i*3+0] + n1*C.c110[i*3+1] + n2*C.c110[i*3+2];
#pragma unroll
  for (int i = 0; i < 3; i++)
#pragma unroll
    for (int k = 0; k < 5; k++)
      cn[6+i*5+k] = n0*C.c112[(i*3+0)*5+k] + n1*C.c112[(i*3+1)*5+k] + n2*C.c112[(i*3+2)*5+k];
#pragma unroll
  for (int i = 0; i < 5; i++)
#pragma unroll
    for (int k = 0; k < 3; k++)
      cn[21+i*3+k] = n0*C.c211[(i*3+0)*3+k] + n1*C.c211[(i*3+1)*3+k] + n2*C.c211[(i*3+2)*3+k];
}

__global__ __launch_bounds__(256) void k_h_init(
    const float* __restrict__ x, const float* __restrict__ wi, float* __restrict__ HT) {
  int n = blockIdx.x * 256 + threadIdx.x;
  int e = blockIdx.y;
  if (n >= NN) return;
  float v = 0.f;
  if (e < 64)
    v = (x[n*3+0]*wi[0*64+e] + x[n*3+1]*wi[64+e] + x[n*3+2]*wi[128+e]) * 0.57735026918962576f;
  HT[e*NN + n] = v;
}

__global__ __launch_bounds__(256) void k_node_pre(
    const float* __restrict__ HT, const float* __restrict__ Wm, const float* __restrict__ Wl,
    CMsgPre C, float* __restrict__ Z) {
  int n = blockIdx.x * 256 + threadIdx.x;
  int widx = blockIdx.y;
  if (n >= NN) return;
  float acc = 0.f;
  if (widx < 64) {
    int w = widx;
    for (int u = 0; u < 64; u++) acc += HT[u*NN+n] * Wm[u*64+w];
    acc *= C.a000;
  } else if (widx < 96) {
    int w = widx - 64;
    for (int u = 0; u < 64; u++) acc += HT[u*NN+n] * Wm[4096 + u*32+w];
    acc *= C.a011;
  } else if (widx < 192) {
    int t = widx - 96, w = t/3, k = t - w*3;
    for (int u = 0; u < 32; u++) {
      float g = HT[(64+u*3+0)*NN+n]*C.c101[0*3+k]
              + HT[(64+u*3+1)*NN+n]*C.c101[1*3+k]
              + HT[(64+u*3+2)*NN+n]*C.c101[2*3+k];
      acc += Wm[6144 + u*32+w] * g;
    }
  } else if (widx < 384) {
    int t = widx - 192, w = t/3, i = t - w*3;
    for (int u = 0; u < 32; u++) acc += HT[(64+u*3+i)*NN+n] * Wm[7168 + u*64+w];
    acc *= C.a110;
  } else if (widx < 432) {
    int t = widx - 384, w = t/3, i = t - w*3;
    for (int u = 0; u < 32; u++) acc += HT[(64+u*3+i)*NN+n] * Wm[9216 + u*16+w];
    acc *= C.a112;
  } else if (widx < 512) {
    int t = widx - 432, w = t/5, k = t - w*5;
    for (int u = 0; u < 16; u++) {
      float g = 0.f;
#pragma unroll
      for (int i = 0; i < 5; i++) g += HT[(160+u*5+i)*NN+n] * C.c202[i*5+k];
      acc += Wm[9728 + u*16+w] * g;
    }
  } else if (widx < 672) {
    int t = widx - 512, w = t/5, i = t - w*5;
    for (int u = 0; u < 16; u++) acc += HT[(160+u*5+i)*NN+n] * Wm[9984 + u*32+w];
    acc *= C.a211;
  } else {
    int e2 = widx - 672;
    if (e2 < 64) {
      for (int u = 0; u < 64; u++) acc += HT[u*NN+n] * Wl[u*64+e2];
      acc *= 0.125f;
    } else if (e2 < 160) {
      int t = e2 - 64, v = t/3, i = t - v*3;
      for (int u = 0; u < 32; u++) acc += HT[(64+u*3+i)*NN+n] * Wl[4096 + u*32+v];
      acc *= 0.17677669529663687f;
    } else {
      int t = e2 - 160, v = t/5, i = t - v*5;
      for (int u = 0; u < 16; u++) acc += HT[(160+u*5+i)*NN+n] * Wl[5120 + u*16+v];
      acc *= 0.25f;
    }
  }
  Z[(size_t)n*ZD + widx] = acc;
}

__global__ __launch_bounds__(256) void k_edge(
    const int* __restrict__ ei, const float* __restrict__ EA, const float* __restrict__ CN,
    const float* __restrict__ Z, float* __restrict__ AGG) {
  __shared__ float zsh[4][ZD];
  int lane = threadIdx.x & 63, wid = threadIdx.x >> 6;
  int wg = blockIdx.x * 4 + wid;
  int stride = gridDim.x * 4;
  int iters = (NE + stride - 1) / stride;
  for (int it = 0; it < iters; ++it) {
    int e = wg + it * stride;
    bool act = e < NE;
    int r = 0;
    float s = 0.f;
    const float* cn = CN;
    if (act) {
      r = ei[e];
      int c = ei[NE + e];
      s = EA[e*4];
      cn = CN + (size_t)e*36;
      const float* zr = Z + (size_t)c*ZD;
      for (int t = lane; t < ZD; t += 64) zsh[wid][t] = zr[t];
    }
    __syncthreads();
    if (act) {
      const float* z = zsh[wid];
#pragma unroll
      for (int j = 0; j < 4; j++) {
        int idx = lane + 64*j;
        if (idx < HD) {
          float y = z[672 + idx];
          if (idx < 64) {
            int w = idx;
            y += s * z[w];
#pragma unroll
            for (int i = 0; i < 3; i++) y += z[192 + w*3 + i] * cn[3+i];
          } else if (idx < 160) {
            int t = idx - 64, w = t/3, k = t - w*3;
            y += cn[k] * z[64 + w] + s * z[96 + t];
#pragma unroll
            for (int i = 0; i < 5; i++) y += z[512 + w*5 + i] * cn[21 + i*3 + k];
          } else {
            int t = idx - 160, w = t/5, k = t - w*5;
            y += s * z[432 + t];
#pragma unroll
            for (int i = 0; i < 3; i++) y += z[384 + w*3 + i] * cn[6 + i*5 + k];
          }
          atomicAdd(&AGG[(size_t)r*HD + idx], y);
        }
      }
    }
    __syncthreads();
  }
}

__global__ __launch_bounds__(256) void k_transpose(
    const float* __restrict__ A_nm, float* __restrict__ A_t) {
  int n = blockIdx.x * 256 + threadIdx.x;
  int e = blockIdx.y;
  if (n >= NN) return;
  A_t[e*NN + n] = A_nm[(size_t)n*HD + e];
}

// ---------- unified update-TP kernel: 384 homogeneous pieces ----------
// piece = blockIdx.y; rc = piece&3 (reduction quarter), pt = piece>>2:
//   pt  0-15: (000) w4   16-31: (110) w4   32-47: (220) w4
//   pt 48-55: (011) w4   56-63: (101) w4   64-71: (121) w4   72-79: (211) w4
//   pt 80-83: (022) w4   84-87: (202) w4   88-91: (112) w4   92-95: (222) w4
// Each block stages its weight sub-tile to LDS, computes a PARTIAL reduction
// for 256 nodes (NPT=2, 128 threads), atomicAdds into UPD (pre-zeroed).
__global__ __launch_bounds__(128, 4) void k_upd(
    const float* __restrict__ A,   // HT  (h, elem-major)
    const float* __restrict__ B,   // AGT (agg, elem-major)
    const float* __restrict__ W,
    CUpdS CS, CUpdD CD, CUpdP CP,
    float* __restrict__ UPD) {
  __shared__ float4 lds4[1024];
  const int tid = threadIdx.x;
  const int n0 = blockIdx.x * 256 + tid;
  const int n1 = n0 + 128;
  const bool ok0 = n0 < NN, ok1 = n1 < NN;
  const int nc0 = ok0 ? n0 : NN - 1;
  const int nc1 = ok1 ? n1 : NN - 1;
  const int piece = blockIdx.y;
  const int rc = piece & 3;
  const int pt = piece >> 2;
  const float4* W4 = (const float4*)W;

#define LDA2(dst, e) { int _e=(e); dst.x = A[_e*NN+nc0]; dst.y = A[_e*NN+nc1]; }
#define LDB2(dst, e) { int _e=(e); dst.x = B[_e*NN+nc0]; dst.y = B[_e*NN+nc1]; }
#define ATOM2(e, val) { int _e=(e); if (ok0) atomicAdd(&UPD[_e*NN+n0], val.x); if (ok1) atomicAdd(&UPD[_e*NN+n1], val.y); }

  if (pt < 16) {
    // ---- (0,0,0): u-split. u0 = rc*16. stage [16u][64v][w4] = 1024 f4
    const int w04 = pt, u0 = rc << 4;
    for (int t = tid; t < 1024; t += 128)
      lds4[t] = W4[((u0 + (t >> 6)) * 64 + (t & 63)) * 16 + w04];
    __syncthreads();
    float2 ha[16];
#pragma unroll
    for (int u = 0; u < 16; ++u) {
      LDA2(ha[u], u0 + u);
      ha[u].x *= CS.s000; ha[u].y *= CS.s000;
    }
    float2 y[4];
#pragma unroll
    for (int w = 0; w < 4; w++) y[w] = make_float2(0.f, 0.f);
    for (int v = 0; v < 64; ++v) {
      float2 bv; LDB2(bv, v);
#pragma unroll
      for (int u = 0; u < 16; ++u) {
        float4 wl = lds4[u*64 + v];
        float px = ha[u].x * bv.x, qx = ha[u].y * bv.y;
        y[0].x += px*wl.x; y[0].y += qx*wl.x;
        y[1].x += px*wl.y; y[1].y += qx*wl.y;
        y[2].x += px*wl.z; y[2].y += qx*wl.z;
        y[3].x += px*wl.w; y[3].y += qx*wl.w;
      }
    }
#pragma unroll
    for (int w = 0; w < 4; ++w) ATOM2(w04*4 + w, y[w]);

  } else if (pt < 32) {
    // ---- (1,1,0): v-split. v0 = rc*8. stage [32u][8v][w4] = 256 f4. Wf4 base 102400
    const int w04 = pt - 16, v0 = rc << 3;
    for (int t = tid; t < 256; t += 128)
      lds4[t] = W4[102400 + ((t >> 3) * 32 + v0 + (t & 7)) * 16 + w04];
    __syncthreads();
    float2 y[4];
#pragma unroll
    for (int w = 0; w < 4; w++) y[w] = make_float2(0.f, 0.f);
    for (int uc = 0; uc < 4; ++uc) {
      float2 a[8][3];
#pragma unroll
      for (int u = 0; u < 8; ++u)
#pragma unroll
        for (int i = 0; i < 3; ++i) LDA2(a[u][i], 64 + (uc*8+u)*3 + i);
      for (int vl = 0; vl < 8; ++vl) {
        float2 b[3];
#pragma unroll
        for (int j = 0; j < 3; ++j) LDB2(b[j], 64 + (v0+vl)*3 + j);
        float2 bt[3];
#pragma unroll
        for (int i = 0; i < 3; ++i) {
          bt[i].x = CD.c110[i*3+0]*b[0].x + CD.c110[i*3+1]*b[1].x + CD.c110[i*3+2]*b[2].x;
          bt[i].y = CD.c110[i*3+0]*b[0].y + CD.c110[i*3+1]*b[1].y + CD.c110[i*3+2]*b[2].y;
        }
#pragma unroll
        for (int u = 0; u < 8; ++u) {
          float Dx = a[u][0].x*bt[0].x + a[u][1].x*bt[1].x + a[u][2].x*bt[2].x;
          float Dy = a[u][0].y*bt[0].y + a[u][1].y*bt[1].y + a[u][2].y*bt[2].y;
          float4 wl = lds4[(uc*8+u)*8 + vl];
          y[0].x += Dx*wl.x; y[0].y += Dy*wl.x;
          y[1].x += Dx*wl.y; y[1].y += Dy*wl.y;
          y[2].x += Dx*wl.z; y[2].y += Dy*wl.z;
          y[3].x += Dx*wl.w; y[3].y += Dy*wl.w;
        }
      }
    }
#pragma unroll
    for (int w = 0; w < 4; ++w) ATOM2(w04*4 + w, y[w]);

  } else if (pt < 48) {
    // ---- (2,2,0): v-split. v0 = rc*4. stage [16u][4v][w4] = 64 f4. base 135168
    const int w04 = pt - 32, v0 = rc << 2;
    for (int t = tid; t < 64; t += 128)
      lds4[t] = W4[135168 + ((t >> 2) * 16 + v0 + (t & 3)) * 16 + w04];
    __syncthreads();
    float2 y[4];
#pragma unroll
    for (int w = 0; w < 4; w++) y[w] = make_float2(0.f, 0.f);
    for (int uc = 0; uc < 4; ++uc) {
      float2 a[4][5];
#pragma unroll
      for (int u = 0; u < 4; ++u)
#pragma unroll
        for (int i = 0; i < 5; ++i) LDA2(a[u][i], 160 + (uc*4+u)*5 + i);
      for (int vl = 0; vl < 4; ++vl) {
        float2 b[5];
#pragma unroll
        for (int j = 0; j < 5; ++j) LDB2(b[j], 160 + (v0+vl)*5 + j);
        float2 bt[5];
#pragma unroll
        for (int i = 0; i < 5; ++i) {
          float tx = 0.f, ty = 0.f;
#pragma unroll
          for (int j = 0; j < 5; ++j) { tx += CD.c220[i*5+j]*b[j].x; ty += CD.c220[i*5+j]*b[j].y; }
          bt[i].x = tx; bt[i].y = ty;
        }
#pragma unroll
        for (int u = 0; u < 4; ++u) {
          float Dx = 0.f, Dy = 0.f;
#pragma unroll
          for (int i = 0; i < 5; ++i) { Dx += a[u][i].x*bt[i].x; Dy += a[u][i].y*bt[i].y; }
          float4 wl = lds4[(uc*4+u)*4 + vl];
          y[0].x += Dx*wl.x; y[0].y += Dy*wl.x;
          y[1].x += Dx*wl.y; y[1].y += Dy*wl.y;
          y[2].x += Dx*wl.z; y[2].y += Dy*wl.z;
          y[3].x += Dx*wl.w; y[3].y += Dy*wl.w;
        }
      }
    }
#pragma unroll
    for (int w = 0; w < 4; ++w) ATOM2(w04*4 + w, y[w]);

  } else if (pt < 56) {
    // ---- (0,1,1): v-split. v0 = rc*8. stage [64u][8v][w4] = 512 f4. base 65536
    const int w04 = pt - 48, v0 = rc << 3;
    for (int t = tid; t < 512; t += 128)
      lds4[t] = W4[65536 + ((t >> 3) * 32 + v0 + (t & 7)) * 8 + w04];
    __syncthreads();
    float2 y[4][3];
#pragma unroll
    for (int w = 0; w < 4; w++)
#pragma unroll
      for (int k = 0; k < 3; k++) y[w][k] = make_float2(0.f, 0.f);
    for (int uc = 0; uc < 4; ++uc) {
      float2 a[16];
#pragma unroll
      for (int u = 0; u < 16; ++u) LDA2(a[u], uc*16 + u);
      for (int vl = 0; vl < 8; ++vl) {
        float2 b[3];
#pragma unroll
        for (int j = 0; j < 3; ++j) LDB2(b[j], 64 + (v0+vl)*3 + j);
        float2 bc[3];
#pragma unroll
        for (int k = 0; k < 3; ++k) {
          bc[k].x = b[0].x*CS.c011[k] + b[1].x*CS.c011[3+k] + b[2].x*CS.c011[6+k];
          bc[k].y = b[0].y*CS.c011[k] + b[1].y*CS.c011[3+k] + b[2].y*CS.c011[6+k];
        }
        float2 g[4];
#pragma unroll
        for (int w = 0; w < 4; w++) g[w] = make_float2(0.f, 0.f);
#pragma unroll
        for (int u = 0; u < 16; ++u) {
          float4 wl = lds4[(uc*16+u)*8 + vl];
          g[0].x += a[u].x*wl.x; g[0].y += a[u].y*wl.x;
          g[1].x += a[u].x*wl.y; g[1].y += a[u].y*wl.y;
          g[2].x += a[u].x*wl.z; g[2].y += a[u].y*wl.z;
          g[3].x += a[u].x*wl.w; g[3].y += a[u].y*wl.w;
        }
#pragma unroll
        for (int w = 0; w < 4; ++w)
#pragma unroll
          for (int k = 0; k < 3; ++k) {
            y[w][k].x += bc[k].x*g[w].x; y[w][k].y += bc[k].y*g[w].y;
          }
      }
    }
#pragma unroll
    for (int w = 0; w < 4; ++w)
#pragma unroll
      for (int k = 0; k < 3; ++k) ATOM2(64 + (w04*4 + w)*3 + k, y[w][k]);

  } else if (pt < 64) {
    // ---- (1,0,1): v-split. v0 = rc*16. stage [32u][16v][w4] = 512 f4. base 86016
    const int w04 = pt - 56, v0 = rc << 4;
    for (int t = tid; t < 512; t += 128)
      lds4[t] = W4[86016 + ((t >> 4) * 64 + v0 + (t & 15)) * 8 + w04];
    __syncthreads();
    float2 y[4][3];
#pragma unroll
    for (int w = 0; w < 4; w++)
#pragma unroll
      for (int k = 0; k < 3; k++) y[w][k] = make_float2(0.f, 0.f);
    float2 bv[16];
#pragma unroll
    for (int v2 = 0; v2 < 16; ++v2) LDB2(bv[v2], v0 + v2);
    for (int u = 0; u < 32; ++u) {
      float2 aa[3];
#pragma unroll
      for (int i = 0; i < 3; ++i) LDA2(aa[i], 64 + u*3 + i);
      float2 ac[3];
#pragma unroll
      for (int k = 0; k < 3; ++k) {
        ac[k].x = aa[0].x*CS.c101[k] + aa[1].x*CS.c101[3+k] + aa[2].x*CS.c101[6+k];
        ac[k].y = aa[0].y*CS.c101[k] + aa[1].y*CS.c101[3+k] + aa[2].y*CS.c101[6+k];
      }
      float2 gp[4];
#pragma unroll
      for (int w = 0; w < 4; w++) gp[w] = make_float2(0.f, 0.f);
#pragma unroll
      for (int v2 = 0; v2 < 16; ++v2) {
        float4 wl = lds4[u*16 + v2];
        gp[0].x += bv[v2].x*wl.x; gp[0].y += bv[v2].y*wl.x;
        gp[1].x += bv[v2].x*wl.y; gp[1].y += bv[v2].y*wl.y;
        gp[2].x += bv[v2].x*wl.z; gp[2].y += bv[v2].y*wl.z;
        gp[3].x += bv[v2].x*wl.w; gp[3].y += bv[v2].y*wl.w;
      }
#pragma unroll
      for (int w = 0; w < 4; ++w)
#pragma unroll
        for (int k = 0; k < 3; ++k) {
          y[w][k].x += ac[k].x*gp[w].x; y[w][k].y += ac[k].y*gp[w].y;
        }
    }
#pragma unroll
    for (int w = 0; w < 4; ++w)
#pragma unroll
      for (int k = 0; k < 3; ++k) ATOM2(64 + (w04*4 + w)*3 + k, y[w][k]);

  } else if (pt < 72) {
    // ---- (1,2,1): v-split. v0 = rc*4. stage [32u][4v][w4] = 128 f4. base 122880
    const int w04 = pt - 64, v0 = rc << 2;
    for (int t = tid; t < 128; t += 128)
      lds4[t] = W4[122880 + ((t >> 2) * 16 + v0 + (t & 3)) * 8 + w04];
    __syncthreads();
    float2 y[4][3];
#pragma unroll
    for (int w = 0; w < 4; w++)
#pragma unroll
      for (int k = 0; k < 3; k++) y[w][k] = make_float2(0.f, 0.f);
    for (int uc = 0; uc < 4; ++uc) {
      float2 a[8][3];
#pragma unroll
      for (int u = 0; u < 8; ++u)
#pragma unroll
        for (int i = 0; i < 3; ++i) LDA2(a[u][i], 64 + (uc*8+u)*3 + i);
      for (int vl = 0; vl < 4; ++vl) {
        float2 b[5];
#pragma unroll
        for (int j = 0; j < 5; ++j) LDB2(b[j], 160 + (v0+vl)*5 + j);
        float2 bt[3][3];
#pragma unroll
        for (int i = 0; i < 3; ++i)
#pragma unroll
          for (int k = 0; k < 3; ++k) {
            float tx = 0.f, ty = 0.f;
#pragma unroll
            for (int j = 0; j < 5; ++j) { tx += b[j].x*CP.c121[(i*5+j)*3+k]; ty += b[j].y*CP.c121[(i*5+j)*3+k]; }
            bt[i][k].x = tx; bt[i][k].y = ty;
          }
#pragma unroll
        for (int u = 0; u < 8; ++u) {
          float2 P[3];
#pragma unroll
          for (int k = 0; k < 3; ++k) {
            P[k].x = a[u][0].x*bt[0][k].x + a[u][1].x*bt[1][k].x + a[u][2].x*bt[2][k].x;
            P[k].y = a[u][0].y*bt[0][k].y + a[u][1].y*bt[1][k].y + a[u][2].y*bt[2][k].y;
          }
          float4 wl = lds4[(uc*8+u)*4 + vl];
#pragma unroll
          for (int k = 0; k < 3; ++k) {
            y[0][k].x += P[k].x*wl.x; y[0][k].y += P[k].y*wl.x;
            y[1][k].x += P[k].x*wl.y; y[1][k].y += P[k].y*wl.y;
            y[2][k].x += P[k].x*wl.z; y[2][k].y += P[k].y*wl.z;
            y[3][k].x += P[k].x*wl.w; y[3][k].y += P[k].y*wl.w;
          }
        }
      }
    }
#pragma unroll
    for (int w = 0; w < 4; ++w)
#pragma unroll
      for (int k = 0; k < 3; ++k) ATOM2(64 + (w04*4 + w)*3 + k, y[w][k]);

  } else if (pt < 80) {
    // ---- (2,1,1): v-split. v0 = rc*8. stage [16u][8v][w4] = 128 f4. base 131072
    const int w04 = pt - 72, v0 = rc << 3;
    for (int t = tid; t < 128; t += 128)
      lds4[t] = W4[131072 + ((t >> 3) * 32 + v0 + (t & 7)) * 8 + w04];
    __syncthreads();
    float2 y[4][3];
#pragma unroll
    for (int w = 0; w < 4; w++)
#pragma unroll
      for (int k = 0; k < 3; k++) y[w][k] = make_float2(0.f, 0.f);
    for (int uc = 0; uc < 2; ++uc) {
      float2 a[8][5];
#pragma unroll
      for (int u = 0; u < 8; ++u)
#pragma unroll
        for (int i = 0; i < 5; ++i) LDA2(a[u][i], 160 + (uc*8+u)*5 + i);
      for (int vl = 0; vl < 8; ++vl) {
        float2 b[3];
#pragma unroll
        for (int j = 0; j < 3; ++j) LDB2(b[j], 64 + (v0+vl)*3 + j);
        float2 bt[5][3];
#pragma unroll
        for (int i = 0; i < 5; ++i)
#pragma unroll
          for (int k = 0; k < 3; ++k) {
            bt[i][k].x = b[0].x*CP.c211[(i*3+0)*3+k] + b[1].x*CP.c211[(i*3+1)*3+k] + b[2].x*CP.c211[(i*3+2)*3+k];
            bt[i][k].y = b[0].y*CP.c211[(i*3+0)*3+k] + b[1].y*CP.c211[(i*3+1)*3+k] + b[2].y*CP.c211[(i*3+2)*3+k];
          }
#pragma unroll
        for (int u = 0; u < 8; ++u) {
          float2 P[3];
#pragma unroll
          for (int k = 0; k < 3; ++k) {
            float tx = 0.f, ty = 0.f;
#pragma unroll
            for (int i = 0; i < 5; ++i) { tx += a[u][i].x*bt[i][k].x; ty += a[u][i].y*bt[i][k].y; }
            P[k].x = tx; P[k].y = ty;
          }
          float4 wl = lds4[(uc*8+u)*8 + vl];
#pragma unroll
          for (int k = 0; k < 3; ++k) {
            y[0][k].x += P[k].x*wl.x; y[0][k].y += P[k].y*wl.x;
            y[1][k].x += P[k].x*wl.y; y[1][k].y += P[k].y*wl.y;
            y[2][k].x += P[k].x*wl.z; y[2][k].y += P[k].y*wl.z;
            y[3][k].x += P[k].x*wl.w; y[3][k].y += P[k].y*wl.w;
          }
        }
      }
    }
#pragma unroll
    for (int w = 0; w < 4; ++w)
#pragma unroll
      for (int k = 0; k < 3; ++k) ATOM2(64 + (w04*4 + w)*3 + k, y[w][k]);

  } else if (pt < 84) {
    // ---- (0,2,2): v-split. v0 = rc*4. stage [64u][4v][w4] = 256 f4. base 81920
    const int w04 = pt - 80, v0 = rc << 2;
    for (int t = tid; t < 256; t += 128)
      lds4[t] = W4[81920 + ((t >> 2) * 16 + v0 + (t & 3)) * 4 + w04];
    __syncthreads();
    float2 y[4][5];
#pragma unroll
    for (int w = 0; w < 4; w++)
#pragma unroll
      for (int k = 0; k < 5; k++) y[w][k] = make_float2(0.f, 0.f);
    for (int uc = 0; uc < 4; ++uc) {
      float2 a[16];
#pragma unroll
      for (int u = 0; u < 16; ++u) LDA2(a[u], uc*16 + u);
      for (int vl = 0; vl < 4; ++vl) {
        float2 b[5];
#pragma unroll
        for (int j = 0; j < 5; ++j) LDB2(b[j], 160 + (v0+vl)*5 + j);
        float2 bc[5];
#pragma unroll
        for (int k = 0; k < 5; ++k) {
          float tx = 0.f, ty = 0.f;
#pragma unroll
          for (int j = 0; j < 5; ++j) { tx += b[j].x*CS.c022[j*5+k]; ty += b[j].y*CS.c022[j*5+k]; }
          bc[k].x = tx; bc[k].y = ty;
        }
        float2 g[4];
#pragma unroll
        for (int w = 0; w < 4; w++) g[w] = make_float2(0.f, 0.f);
#pragma unroll
        for (int u = 0; u < 16; ++u) {
          float4 wl = lds4[(uc*16+u)*4 + vl];
          g[0].x += a[u].x*wl.x; g[0].y += a[u].y*wl.x;
          g[1].x += a[u].x*wl.y; g[1].y += a[u].y*wl.y;
          g[2].x += a[u].x*wl.z; g[2].y += a[u].y*wl.z;
          g[3].x += a[u].x*wl.w; g[3].y += a[u].y*wl.w;
        }
#pragma unroll
        for (int w = 0; w < 4; ++w)
#pragma unroll
          for (int k = 0; k < 5; ++k) {
            y[w][k].x += bc[k].x*g[w].x; y[w][k].y += bc[k].y*g[w].y;
          }
      }
    }
#pragma unroll
    for (int w = 0; w < 4; ++w)
#pragma unroll
      for (int k = 0; k < 5; ++k) ATOM2(160 + (w04*4 + w)*5 + k, y[w][k]);

  } else if (pt < 88) {
    // ---- (2,0,2): v-split. v0 = rc*16. stage [16u][16v][w4] = 256 f4. base 126976
    const int w04 = pt - 84, v0 = rc << 4;
    for (int t = tid; t < 256; t += 128)
      lds4[t] = W4[126976 + ((t >> 4) * 64 + v0 + (t & 15)) * 4 + w04];
    __syncthreads();
    float2 y[4][5];
#pragma unroll
    for (int w = 0; w < 4; w++)
#pragma unroll
      for (int k = 0; k < 5; k++) y[w][k] = make_float2(0.f, 0.f);
    float2 bv[16];
#pragma unroll
    for (int v2 = 0; v2 < 16; ++v2) LDB2(bv[v2], v0 + v2);
    for (int u = 0; u < 16; ++u) {
      float2 aa[5];
#pragma unroll
      for (int i = 0; i < 5; ++i) LDA2(aa[i], 160 + u*5 + i);
      float2 ac[5];
#pragma unroll
      for (int k = 0; k < 5; ++k) {
        float tx = 0.f, ty = 0.f;
#pragma unroll
        for (int i = 0; i < 5; ++i) { tx += aa[i].x*CS.c202[i*5+k]; ty += aa[i].y*CS.c202[i*5+k]; }
        ac[k].x = tx; ac[k].y = ty;
      }
      float2 gp[4];
#pragma unroll
      for (int w = 0; w < 4; w++) gp[w] = make_float2(0.f, 0.f);
#pragma unroll
      for (int v2 = 0; v2 < 16; ++v2) {
        float4 wl = lds4[u*16 + v2];
        gp[0].x += bv[v2].x*wl.x; gp[0].y += bv[v2].y*wl.x;
        gp[1].x += bv[v2].x*wl.y; gp[1].y += bv[v2].y*wl.y;
        gp[2].x += bv[v2].x*wl.z; gp[2].y += bv[v2].y*wl.z;
        gp[3].x += bv[v2].x*wl.w; gp[3].y += bv[v2].y*wl.w;
      }
#pragma unroll
      for (int w = 0; w < 4; ++w)
#pragma unroll
        for (int k = 0; k < 5; ++k) {
          y[w][k].x += ac[k].x*gp[w].x; y[w][k].y += ac[k].y*gp[w].y;
        }
    }
#pragma unroll
    for (int w = 0; w < 4; ++w)
#pragma unroll
      for (int k = 0; k < 5; ++k) ATOM2(160 + (w04*4 + w)*5 + k, y[w][k]);

  } else if (pt < 92) {
    // ---- (1,1,2): v-split. v0 = rc*8. stage [32u][8v][w4] = 256 f4. base 118784
    const int w04 = pt - 88, v0 = rc << 3;
    for (int t = tid; t < 256; t += 128)
      lds4[t] = W4[118784 + ((t >> 3) * 32 + v0 + (t & 7)) * 4 + w04];
    __syncthreads();
    float2 y[4][5];
#pragma unroll
    for (int w = 0; w < 4; w++)
#pragma unroll
      for (int k = 0; k < 5; k++) y[w][k] = make_float2(0.f, 0.f);
    for (int uc = 0; uc < 4; ++uc) {
      float2 a[8][3];
#pragma unroll
      for (int u = 0; u < 8; ++u)
#pragma unroll
        for (int i = 0; i < 3; ++i) LDA2(a[u][i], 64 + (uc*8+u)*3 + i);
      for (int vl = 0; vl < 8; ++vl) {
        float2 b[3];
#pragma unroll
        for (int j = 0; j < 3; ++j) LDB2(b[j], 64 + (v0+vl)*3 + j);
        float2 bt[3][5];
#pragma unroll
        for (int i = 0; i < 3; ++i)
#pragma unroll
          for (int k = 0; k < 5; ++k) {
            bt[i][k].x = b[0].x*CP.c112[(i*3+0)*5+k] + b[1].x*CP.c112[(i*3+1)*5+k] + b[2].x*CP.c112[(i*3+2)*5+k];
            bt[i][k].y = b[0].y*CP.c112[(i*3+0)*5+k] + b[1].y*CP.c112[(i*3+1)*5+k] + b[2].y*CP.c112[(i*3+2)*5+k];
          }
#pragma unroll
        for (int u = 0; u < 8; ++u) {
          float2 P[5];
#pragma unroll
          for (int k = 0; k < 5; ++k) {
            P[k].x = a[u][0].x*bt[0][k].x + a[u][1].x*bt[1][k].x + a[u][2].x*bt[2][k].x;
            P[k].y = a[u][0].y*bt[0][k].y + a[u][1].y*bt[1][k].y + a[u][2].y*bt[2][k].y;
          }
          float4 wl = lds4[(uc*8+u)*8 + vl];
#pragma unroll
          for (int k = 0; k < 5; ++k) {
            y[0][k].x += P[k].x*wl.x; y[0][k].y += P[k].y*wl.x;
            y[1][k].x += P[k].x*wl.y; y[1][k].y += P[k].y*wl.y;
            y[2][k].x += P[k].x*wl.z; y[2][k].y += P[k].y*wl.z;
            y[3][k].x += P[k].x*wl.w; y[3][k].y += P[k].y*wl.w;
          }
        }
      }
    }
#pragma unroll
    for (int w = 0; w < 4; ++w)
#pragma unroll
      for (int k = 0; k < 5; ++k) ATOM2(160 + (w04*4 + w)*5 + k, y[w][k]);

  } else {
    // ---- (2,2,2): v-split. v0 = rc*4. stage [16u][4v][w4] = 64 f4. base 139264
    const int w04 = pt - 92, v0 = rc << 2;
    for (int t = tid; t < 64; t += 128)
      lds4[t] = W4[139264 + ((t >> 2) * 16 + v0 + (t & 3)) * 4 + w04];
    __syncthreads();
    float2 y[4][5];
#pragma unroll
    for (int w = 0; w < 4; w++)
#pragma unroll
      for (int k = 0; k < 5; k++) y[w][k] = make_float2(0.f, 0.f);
    for (int vl = 0; vl < 4; ++vl) {
      float2 b[5];
#pragma unroll
      for (int j = 0; j < 5; ++j) LDB2(b[j], 160 + (v0+vl)*5 + j);
      float2 bt[5][5];
#pragma unroll
      for (int i = 0; i < 5; ++i)
#pragma unroll
        for (int k = 0; k < 5; ++k) {
          float tx = 0.f, ty = 0.f;
#pragma unroll
          for (int j = 0; j < 5; ++j) { tx += b[j].x*CP.c222[(i*5+j)*5+k]; ty += b[j].y*CP.c222[(i*5+j)*5+k]; }
          bt[i][k].x = tx; bt[i][k].y = ty;
        }
      for (int u = 0; u < 16; ++u) {
        float2 aa[5];
#pragma unroll
        for (int i = 0; i < 5; ++i) LDA2(aa[i], 160 + u*5 + i);
        float2 P[5];
#pragma unroll
        for (int k = 0; k < 5; ++k) {
          float tx = 0.f, ty = 0.f;
#pragma unroll
          for (int i = 0; i < 5; ++i) { tx += aa[i].x*bt[i][k].x; ty += aa[i].y*bt[i][k].y; }
          P[k].x = tx; P[k].y = ty;
        }
        float4 wl = lds4[u*4 + vl];
#pragma unroll
        for (int k = 0; k < 5; ++k) {
          y[0][k].x += P[k].x*wl.x; y[0][k].y += P[k].y*wl.x;
          y[1][k].x += P[k].x*wl.y; y[1][k].y += P[k].y*wl.y;
          y[2][k].x += P[k].x*wl.z; y[2][k].y += P[k].y*wl.z;
          y[3][k].x += P[k].x*wl.w; y[3][k].y += P[k].y*wl.w;
        }
      }
    }
#pragma unroll
    for (int w = 0; w < 4; ++w)
#pragma unroll
      for (int k = 0; k < 5; ++k) ATOM2(160 + (w04*4 + w)*5 + k, y[w][k]);
  }
#undef LDA2
#undef LDB2
#undef ATOM2
}

// h_new = h + upd_tp + lin_upd(h)
__global__ __launch_bounds__(256) void k_apply(
    const float* __restrict__ Hsrc, const float* __restrict__ UPD,
    const float* __restrict__ Wl, float* __restrict__ Hdst) {
  int n = blockIdx.x * 256 + threadIdx.x;
  int e = blockIdx.y;
  if (n >= NN) return;
  float lin = 0.f;
  if (e < 64) {
    for (int u = 0; u < 64; u++) lin += Hsrc[u*NN+n] * Wl[u*64+e];
    lin *= 0.125f;
  } else if (e < 160) {
    int t = e - 64, v = t/3, i = t - v*3;
    for (int u = 0; u < 32; u++) lin += Hsrc[(64+u*3+i)*NN+n] * Wl[4096 + u*32+v];
    lin *= 0.17677669529663687f;
  } else {
    int t = e - 160, v = t/5, i = t - v*5;
    for (int u = 0; u < 16; u++) lin += Hsrc[(160+u*5+i)*NN+n] * Wl[5120 + u*16+v];
    lin *= 0.25f;
  }
  Hdst[e*NN + n] = Hsrc[e*NN + n] + UPD[e*NN + n] + lin;
}

__global__ __launch_bounds__(256) void k_cnt(const int* __restrict__ batch, float* __restrict__ CNT) {
  int n = blockIdx.x * 256 + threadIdx.x;
  if (n >= NN) return;
  atomicAdd(&CNT[batch[n]], 1.0f);
}

__global__ __launch_bounds__(256) void k_pool(
    const float* __restrict__ HT, const int* __restrict__ batch, float* __restrict__ POOL) {
  int n = blockIdx.x * 256 + threadIdx.x;
  int w = blockIdx.y;
  if (n >= NN) return;
  atomicAdd(&POOL[batch[n]*64 + w], HT[w*NN + n]);
}

__global__ __launch_bounds__(256) void k_out(
    const float* __restrict__ POOL, const float* __restrict__ CNT,
    const float* __restrict__ wf, float* __restrict__ out) {
  int tid = blockIdx.x * 256 + threadIdx.x;
  if (tid >= NG * 128) return;
  int g = tid >> 7, d = tid & 127;
  float inv = 1.0f / fmaxf(CNT[g], 1.0f);
  float acc = 0.f;
  for (int w = 0; w < 64; w++) acc += POOL[g*64 + w] * wf[w*128 + d];
  out[tid] = acc * inv * 0.125f;
}

// ---------------- host-side real Wigner-3j (mirrors the reference) ----------------
typedef std::complex<double> cd;
static double hfact(int nn) { double f = 1; for (int i = 2; i <= nn; i++) f *= i; return f; }
static double hcg(int j1,int m1,int j2,int m2,int j3,int m3) {
  if (m1 + m2 != m3) return 0.0;
  double pre = sqrt((2*j3+1) * hfact(j3+j1-j2) * hfact(j3-j1+j2) * hfact(j1+j2-j3) / hfact(j1+j2+j3+1));
  pre *= sqrt(hfact(j3+m3)*hfact(j3-m3)*hfact(j1-m1)*hfact(j1+m1)*hfact(j2-m2)*hfact(j2+m2));
  double s = 0;
  for (int k = 0; k <= j1+j2-j3; k++) {
    int a1=j1+j2-j3-k, a2=j1-m1-k, a3=j2+m2-k, a4=j3-j2+m1+k, a5=j3-j1-m2+k;
    if (a1<0||a2<0||a3<0||a4<0||a5<0) continue;
    s += ((k&1)?-1.0:1.0) / (hfact(k)*hfact(a1)*hfact(a2)*hfact(a3)*hfact(a4)*hfact(a5));
  }
  return pre * s;
}
static void hA(int l, cd A[5][5]) {
  for (int r = 0; r < 5; r++) for (int c = 0; c < 5; c++) A[r][c] = cd(0,0);
  A[l][l] = cd(1,0);
  for (int m = 1; m <= l; m++) {
    double sg = (m & 1) ? -1.0 : 1.0;
    A[l+m][l+m] = cd(sg/sqrt(2.0), 0);
    A[l+m][l-m] = cd(1.0/sqrt(2.0), 0);
    A[l-m][l+m] = cd(0, -sg/sqrt(2.0));
    A[l-m][l-m] = cd(0, 1.0/sqrt(2.0));
  }
}
static void hw3j(int l1, int l2, int l3, double* out) {
  int n1 = 2*l1+1, n2 = 2*l2+1, n3 = 2*l3+1;
  double Wc[5][5][5]; memset(Wc, 0, sizeof Wc);
  for (int m1 = -l1; m1 <= l1; m1++) for (int m2 = -l2; m2 <= l2; m2++) {
    int m3 = -(m1+m2);
    if (m3 < -l3 || m3 > l3) continue;
    int ex = l1 - l2 - m3;
    double sg = (ex % 2 == 0) ? 1.0 : -1.0;
    Wc[m1+l1][m2+l2][m3+l3] = sg / sqrt((double)(2*l3+1)) * hcg(l1,m1,l2,m2,l3,-m3);
  }
  cd A1[5][5], A2[5][5], A3[5][5];
  hA(l1,A1); hA(l2,A2); hA(l3,A3);
  double nrm = 0;
  for (int a = 0; a < n1; a++) for (int b = 0; b < n2; b++) for (int c = 0; c < n3; c++) {
    cd acc(0,0);
    for (int d = 0; d < n1; d++) for (int e = 0; e < n2; e++) for (int f = 0; f < n3; f++) {
      double w = Wc[d][e][f];
      if (w == 0.0) continue;
      acc += A1[a][d] * A2[b][e] * A3[c][f] * w;
    }
    out[(a*n2+b)*n3+c] = acc.real();
    nrm += acc.real() * acc.real();
  }
  nrm = sqrt(nrm);
  for (int i = 0; i < n1*n2*n3; i++) out[i] /= nrm;
}

// ---------------- launch ----------------
extern "C" void kernel_launch(void* const* d_in, const int* in_sizes, int n_in,
                              void* d_out, int out_size, void* d_ws, size_t ws_size,
                              hipStream_t stream) {
  const float* x        = (const float*)d_in[0];
  const float* pos      = (const float*)d_in[1];
  const float* w_init   = (const float*)d_in[2];
  const float* w_tp_msg = (const float*)d_in[3];
  const float* w_lin_msg= (const float*)d_in[4];
  const float* w_tp_upd = (const float*)d_in[5];
  const float* w_lin_upd= (const float*)d_in[6];
  const float* w_final  = (const float*)d_in[7];
  const int*   ei       = (const int*)d_in[8];
  const int*   batch    = (const int*)d_in[9];
  float* out = (float*)d_out;
  float* ws  = (float*)d_ws;

  // workspace layout (floats)
  float* EA     = ws;                      // 640000
  float* CN     = EA + 640000;             // 5760000
  float* HTA    = CN + 5760000;            // 2400000
  float* HTB    = HTA + 2400000;           // 2400000
  float* Z      = HTB + 2400000;           // 9120000
  float* AGG_NM = Z + 9120000;             // 2400000
  float* UPD_T  = AGG_NM + 2400000;        // 2400000 (contiguous with AGG_NM for one memset)
  float* AGG_T  = UPD_T + 2400000;         // 2400000
  float* POOL   = AGG_T + 2400000;         // 4096
  float* CNT    = POOL + 4096;             // 64

  // ---- host: compute real-w3j tensors and fill coefficient structs ----
  double C000d[1], C011d[9], C101d[9], C110d[9], C112d[45], C022d[25],
         C202d[25], C121d[45], C211d[45], C220d[25], C222d[125];
  hw3j(0,0,0,C000d); hw3j(0,1,1,C011d); hw3j(1,0,1,C101d); hw3j(1,1,0,C110d);
  hw3j(1,1,2,C112d); hw3j(0,2,2,C022d); hw3j(2,0,2,C202d); hw3j(1,2,1,C121d);
  hw3j(2,1,1,C211d); hw3j(2,2,0,C220d); hw3j(2,2,2,C222d);

  CMsgPre cmsg;
  cmsg.a000 = (float)(C000d[0] / sqrt(128.0));
  cmsg.a011 = (float)(1.0 / sqrt(192.0));
  cmsg.a110 = (float)(1.0 / sqrt(64.0));
  cmsg.a112 = (float)(1.0 / sqrt(64.0));
  cmsg.a211 = (float)(1.0 / sqrt(48.0));
  for (int i = 0; i < 9;  i++) cmsg.c101[i] = (float)(C101d[i] / sqrt(96.0));
  for (int i = 0; i < 25; i++) cmsg.c202[i] = (float)(C202d[i] / sqrt(32.0));

  CEdge ce;
  for (int i = 0; i < 9;  i++) ce.c011[i] = (float)C011d[i];
  for (int i = 0; i < 9;  i++) ce.c110[i] = (float)C110d[i];
  for (int i = 0; i < 45; i++) ce.c112[i] = (float)C112d[i];
  for (int i = 0; i < 45; i++) ce.c211[i] = (float)C211d[i];

  CUpdS cus;
  cus.s000 = (float)(C000d[0] / sqrt(64.0*64.0*3.0));
  for (int i = 0; i < 9;  i++) cus.c011[i] = (float)(C011d[i] / sqrt(64.0*32.0*4.0));
  for (int i = 0; i < 25; i++) cus.c022[i] = (float)(C022d[i] / sqrt(64.0*16.0*4.0));
  for (int i = 0; i < 9;  i++) cus.c101[i] = (float)(C101d[i] / sqrt(32.0*64.0*4.0));
  for (int i = 0; i < 25; i++) cus.c202[i] = (float)(C202d[i] / sqrt(16.0*64.0*4.0));

  CUpdD cud;
  for (int i = 0; i < 9;  i++) cud.c110[i] = (float)(C110d[i] / sqrt(32.0*32.0*3.0));
  for (int i = 0; i < 25; i++) cud.c220[i] = (float)(C220d[i] / sqrt(16.0*16.0*3.0));

  CUpdP cup;
  for (int i = 0; i < 45;  i++) cup.c112[i] = (float)(C112d[i] / sqrt(32.0*32.0*4.0));
  for (int i = 0; i < 45;  i++) cup.c121[i] = (float)(C121d[i] / sqrt(32.0*16.0*4.0));
  for (int i = 0; i < 45;  i++) cup.c211[i] = (float)(C211d[i] / sqrt(16.0*32.0*4.0));
  for (int i = 0; i < 125; i++) cup.c222[i] = (float)(C222d[i] / sqrt(16.0*16.0*4.0));

  // ---- launches ----
  k_edge_attr<<<(NE+255)/256, 256, 0, stream>>>(pos, ei, ce, EA, CN);
  k_h_init<<<dim3(40, HD), 256, 0, stream>>>(x, w_init, HTA);

  float* cur = HTA;
  float* nxt = HTB;
  for (int L = 0; L < 6; L++) {
    hipMemsetAsync(AGG_NM, 0, (size_t)4800000 * sizeof(float), stream); // AGG_NM + UPD_T
    k_node_pre<<<dim3(40, ZD), 256, 0, stream>>>(cur, w_tp_msg + (size_t)L*MSG_WS,
                                                 w_lin_msg + (size_t)L*LIN_WS, cmsg, Z);
    k_edge<<<1280, 256, 0, stream>>>(ei, EA, CN, Z, AGG_NM);
    k_transpose<<<dim3(40, HD), 256, 0, stream>>>(AGG_NM, AGG_T);
    const float* Wu = w_tp_upd + (size_t)L*UPD_WS;
    k_upd<<<dim3(40, 384), 128, 0, stream>>>(cur, AGG_T, Wu, cus, cud, cup, UPD_T);
    k_apply<<<dim3(40, HD), 256, 0, stream>>>(cur, UPD_T, w_lin_upd + (size_t)L*LIN_WS, nxt);
    float* tmp = cur; cur = nxt; nxt = tmp;
  }

  hipMemsetAsync(POOL, 0, (size_t)(4096 + 64) * sizeof(float), stream);
  k_cnt<<<(NN+255)/256, 256, 0, stream>>>(batch, CNT);
  k_pool<<<dim3(40, 64), 256, 0, stream>>>(cur, batch, POOL);
  k_out<<<32, 256, 0, stream>>>(POOL, CNT, w_final, out);
}